// Round 1
// baseline (3401.087 us; speedup 1.0000x reference)
//
#include <hip/hip_runtime.h>
#include <hip/hip_bf16.h>

typedef unsigned short u16;

#define DEV __device__ __forceinline__

// ---------- bf16 helpers (storage only; all math in f32) ----------
DEV float b2f(u16 s){ return __uint_as_float(((unsigned)s) << 16); }
DEV u16 f2b(float f){
    unsigned u = __float_as_uint(f);
    u = u + 0x7fffu + ((u >> 16) & 1u);   // round-to-nearest-even
    return (u16)(u >> 16);
}

DEV float4 loadA4(const float* p){ return *(const float4*)p; }
DEV float4 loadA4(const u16* p){
    ushort4 u = *(const ushort4*)p;
    float4 v; v.x = b2f(u.x); v.y = b2f(u.y); v.z = b2f(u.z); v.w = b2f(u.w);
    return v;
}
DEV void store4(float* p, float a, float b, float c, float d){
    float4 v; v.x = a; v.y = b; v.z = c; v.w = d;
    *(float4*)p = v;
}
DEV void store4(u16* p, float a, float b, float c, float d){
    ushort4 v; v.x = f2b(a); v.y = f2b(b); v.z = f2b(c); v.w = f2b(d);
    *(ushort4*)p = v;
}

template<int ACT> DEV float actf(float x){
    if (ACT == 1) return fmaxf(x, 0.f);
    if (ACT == 2) return 0.5f * x * (1.f + erff(x * 0.70710678118654752f)); // exact GELU
    return x;
}

DEV float red32(float v){
    v += __shfl_xor(v, 16, 32);
    v += __shfl_xor(v, 8, 32);
    v += __shfl_xor(v, 4, 32);
    v += __shfl_xor(v, 2, 32);
    v += __shfl_xor(v, 1, 32);
    return v;
}

// ---------- feature transpose: (n,C,H,W) -> (n,H,W,C), per level ----------
__global__ void transpose_feat(const float* __restrict__ in, float* __restrict__ out,
                               int H, int W){
    int total = 6 * H * W * 32;                // float4 units
    int lin = blockIdx.x * 256 + threadIdx.x;
    if (lin >= total) return;
    int c4   = (lin & 31) * 4;
    int pix  = lin >> 5;
    int x    = pix % W;
    int rest = pix / W;
    int y    = rest % H;
    int n    = rest / H;
    int HW   = H * W;
    size_t ib = ((size_t)(n * 128 + c4) * H + y) * W + x;
    float4 v;
    v.x = in[ib];
    v.y = in[ib + (size_t)HW];
    v.z = in[ib + (size_t)2 * HW];
    v.w = in[ib + (size_t)3 * HW];
    *(float4*)&out[(size_t)pix * 128 + c4] = v;
}

// ---------- position embedding: relu(pos@W1+b1)@W2+b2, 8 queries/block ----------
__global__ __launch_bounds__(256) void pos_embed_kernel(
    const float* __restrict__ bev_pos,
    const float* __restrict__ w1, const float* __restrict__ b1,
    const float* __restrict__ w2, const float* __restrict__ b2,
    float* __restrict__ pos){
    __shared__ float hid[8][256];
    const int t = threadIdx.x;
    const int q0 = blockIdx.x * 8;
    float wa = w1[t], wb = w1[256 + t], wc = w1[512 + t], bb = b1[t];
#pragma unroll
    for (int qq = 0; qq < 8; qq++){
        float p0 = bev_pos[(q0 + qq) * 3 + 0];
        float p1 = bev_pos[(q0 + qq) * 3 + 1];
        float p2 = bev_pos[(q0 + qq) * 3 + 2];
        hid[qq][t] = fmaxf(p0 * wa + p1 * wb + p2 * wc + bb, 0.f);
    }
    __syncthreads();
    const int oc = t & 127;
    const int qg = (t >> 7) * 4;
    float a0 = 0, a1 = 0, a2 = 0, a3 = 0;
    for (int k = 0; k < 256; k++){
        float w = w2[k * 128 + oc];
        a0 += hid[qg + 0][k] * w;
        a1 += hid[qg + 1][k] * w;
        a2 += hid[qg + 2][k] * w;
        a3 += hid[qg + 3][k] * w;
    }
    float bo = b2[oc];
    pos[(size_t)(q0 + qg + 0) * 128 + oc] = a0 + bo;
    pos[(size_t)(q0 + qg + 1) * 128 + oc] = a1 + bo;
    pos[(size_t)(q0 + qg + 2) * 128 + oc] = a2 + bo;
    pos[(size_t)(q0 + qg + 3) * 128 + oc] = a3 + bo;
}

// ---------- generic GEMM: C[M,Ntot] = act(A[M,K] (+add2) @ W[K,Ntot] + bias) ----------
// grid = (M/64, Ntot/128), block = 256. Thread: 8 rows x 4 cols.
template<int K, int ACT, bool ADD2, typename TIN, typename TOUT>
__global__ __launch_bounds__(256) void gemm_kernel(
    const TIN* __restrict__ A, const float* __restrict__ W,
    const float* __restrict__ bias, const float* __restrict__ add2,
    TOUT* __restrict__ C, int Ntot){
    __shared__ float As[64 * 128];
    const int t  = threadIdx.x;
    const int r0 = blockIdx.x * 64;
    const int jb = blockIdx.y * 128;
    const int j0 = (t & 31) * 4;
    const int qg = t >> 5;
    float acc[8][4];
#pragma unroll
    for (int i = 0; i < 8; i++){ acc[i][0] = 0; acc[i][1] = 0; acc[i][2] = 0; acc[i][3] = 0; }

    for (int kc = 0; kc < K; kc += 128){
#pragma unroll
        for (int p = 0; p < 8; p++){
            int lin = p * 256 + t;
            int row = lin >> 5;
            int c4  = (lin & 31) * 4;
            float4 v = loadA4(A + (size_t)(r0 + row) * K + kc + c4);
            if (ADD2){
                float4 w2 = *(const float4*)&add2[(size_t)(r0 + row) * 128 + c4];
                v.x += w2.x; v.y += w2.y; v.z += w2.z; v.w += w2.w;
            }
            *(float4*)&As[row * 128 + c4] = v;
        }
        __syncthreads();
        const float* Wp = W + (size_t)kc * Ntot + jb + j0;
#pragma unroll 4
        for (int k4 = 0; k4 < 128; k4 += 4){
            float4 w0 = *(const float4*)&Wp[(size_t)(k4 + 0) * Ntot];
            float4 w1 = *(const float4*)&Wp[(size_t)(k4 + 1) * Ntot];
            float4 w2 = *(const float4*)&Wp[(size_t)(k4 + 2) * Ntot];
            float4 w3 = *(const float4*)&Wp[(size_t)(k4 + 3) * Ntot];
#pragma unroll
            for (int i = 0; i < 8; i++){
                float4 a = *(const float4*)&As[(qg * 8 + i) * 128 + k4];
                acc[i][0] += a.x * w0.x + a.y * w1.x + a.z * w2.x + a.w * w3.x;
                acc[i][1] += a.x * w0.y + a.y * w1.y + a.z * w2.y + a.w * w3.y;
                acc[i][2] += a.x * w0.z + a.y * w1.z + a.z * w2.z + a.w * w3.z;
                acc[i][3] += a.x * w0.w + a.y * w1.w + a.z * w2.w + a.w * w3.w;
            }
        }
        __syncthreads();
    }
    float4 bv = *(const float4*)&bias[jb + j0];
#pragma unroll
    for (int i = 0; i < 8; i++){
        int r = r0 + qg * 8 + i;
        float o0 = actf<ACT>(acc[i][0] + bv.x);
        float o1 = actf<ACT>(acc[i][1] + bv.y);
        float o2 = actf<ACT>(acc[i][2] + bv.z);
        float o3 = actf<ACT>(acc[i][3] + bv.w);
        store4(C + (size_t)r * Ntot + jb + j0, o0, o1, o2, o3);
    }
}

// ---------- 5x5 SAME conv on 200x200x128, weights HWIO ----------
// grid = 625 (25x25 tiles of 8x8 px), block = 256. Thread: 1 row x 8 cols x 4 oc.
__global__ __launch_bounds__(256) void conv5_kernel(
    const float* __restrict__ in, const float* __restrict__ W,
    const float* __restrict__ bias, float* __restrict__ out){
    __shared__ float P[12 * 12 * 128];
    const int t = threadIdx.x;
    const int bx = blockIdx.x % 25, by = blockIdx.x / 25;
    const int x0 = bx * 8, y0 = by * 8;
#pragma unroll
    for (int it = 0; it < 18; it++){
        int lin = it * 256 + t;
        int c4  = (lin & 31) * 4;
        int pos = lin >> 5;
        int c = pos % 12, r = pos / 12;
        int y = y0 + r - 2, x = x0 + c - 2;
        float4 v; v.x = 0; v.y = 0; v.z = 0; v.w = 0;
        if (y >= 0 && y < 200 && x >= 0 && x < 200)
            v = *(const float4*)&in[((size_t)y * 200 + x) * 128 + c4];
        *(float4*)&P[pos * 128 + c4] = v;
    }
    __syncthreads();
    const int oc = (t & 31) * 4;
    const int g  = t >> 5;
    float acc[8][4];
#pragma unroll
    for (int c = 0; c < 8; c++){ acc[c][0] = 0; acc[c][1] = 0; acc[c][2] = 0; acc[c][3] = 0; }
    for (int tap = 0; tap < 25; tap++){
        const int ky = tap / 5, kx = tap % 5;
        const float* Wt = W + (size_t)tap * 16384 + oc;
        for (int ic = 0; ic < 128; ic += 4){
            float4 w0 = *(const float4*)&Wt[(size_t)(ic + 0) * 128];
            float4 w1 = *(const float4*)&Wt[(size_t)(ic + 1) * 128];
            float4 w2 = *(const float4*)&Wt[(size_t)(ic + 2) * 128];
            float4 w3 = *(const float4*)&Wt[(size_t)(ic + 3) * 128];
#pragma unroll
            for (int c = 0; c < 8; c++){
                float4 a = *(const float4*)&P[((g + ky) * 12 + (c + kx)) * 128 + ic];
                acc[c][0] += a.x * w0.x + a.y * w1.x + a.z * w2.x + a.w * w3.x;
                acc[c][1] += a.x * w0.y + a.y * w1.y + a.z * w2.y + a.w * w3.y;
                acc[c][2] += a.x * w0.z + a.y * w1.z + a.z * w2.z + a.w * w3.z;
                acc[c][3] += a.x * w0.w + a.y * w1.w + a.z * w2.w + a.w * w3.w;
            }
        }
    }
    float4 bv = *(const float4*)&bias[oc];
#pragma unroll
    for (int c = 0; c < 8; c++){
        float4 o;
        o.x = acc[c][0] + bv.x; o.y = acc[c][1] + bv.y;
        o.z = acc[c][2] + bv.z; o.w = acc[c][3] + bv.w;
        *(float4*)&out[((size_t)(y0 + g) * 200 + (x0 + c)) * 128 + oc] = o;
    }
}

// ---------- residual add + LayerNorm over 128, 4 rows/block ----------
__global__ __launch_bounds__(256) void add_ln_kernel(
    const float* __restrict__ a, const float* __restrict__ b,
    const float* __restrict__ gam, const float* __restrict__ bet,
    float* __restrict__ out){
    const int row = blockIdx.x * 4 + (threadIdx.x >> 6);
    const int l   = threadIdx.x & 63;
    const float* pa = a + (size_t)row * 128;
    const float* pb = b + (size_t)row * 128;
    float2 va = *(const float2*)&pa[l * 2];
    float2 vb = *(const float2*)&pb[l * 2];
    float x0 = va.x + vb.x, x1 = va.y + vb.y;
    float s = x0 + x1;
#pragma unroll
    for (int m = 32; m >= 1; m >>= 1) s += __shfl_xor(s, m, 64);
    float mean = s * 0.0078125f;
    float e0 = x0 - mean, e1 = x1 - mean;
    float v = e0 * e0 + e1 * e1;
#pragma unroll
    for (int m = 32; m >= 1; m >>= 1) v += __shfl_xor(v, m, 64);
    float rs = rsqrtf(v * 0.0078125f + 1e-5f);
    float2 vg = *(const float2*)&gam[l * 2];
    float2 vt = *(const float2*)&bet[l * 2];
    float2 o;
    o.x = e0 * rs * vg.x + vt.x;
    o.y = e1 * rs * vg.y + vt.y;
    *(float2*)&out[(size_t)row * 128 + l * 2] = o;
}

// ---------- deformable sampling: q -> flat(Q, P*128) bf16 ----------
// block 256 = 2 queries x 4 points x 32 lanes; lane owns 4 channels.
__global__ __launch_bounds__(256) void sample_kernel(
    const float* __restrict__ q, const float* __restrict__ bev_pos,
    const float* __restrict__ l2i,
    const float* __restrict__ off_w, const float* __restrict__ off_b,
    const float* __restrict__ sw_w, const float* __restrict__ sw_b,
    const float* __restrict__ f0, const float* __restrict__ f1,
    const float* __restrict__ f2, const float* __restrict__ f3,
    u16* __restrict__ flat){
    const int t = threadIdx.x;
    const int lane = t & 31;
    const int p = (t >> 5) & 3;
    const int qi = blockIdx.x * 2 + (t >> 7);
    const int d0 = lane * 4;
    float4 qv = *(const float4*)&q[(size_t)qi * 128 + d0];

    float off[3];
#pragma unroll
    for (int k = 0; k < 3; k++){
        int col = p * 3 + k;
        float s = qv.x * off_w[(d0 + 0) * 12 + col] + qv.y * off_w[(d0 + 1) * 12 + col]
                + qv.z * off_w[(d0 + 2) * 12 + col] + qv.w * off_w[(d0 + 3) * 12 + col];
        off[k] = red32(s) + off_b[col];
    }
    float swv[4];
    {
        float lg[4];
#pragma unroll
        for (int lv = 0; lv < 4; lv++){
            int col = p * 4 + lv;
            float s = qv.x * sw_w[(d0 + 0) * 16 + col] + qv.y * sw_w[(d0 + 1) * 16 + col]
                    + qv.z * sw_w[(d0 + 2) * 16 + col] + qv.w * sw_w[(d0 + 3) * 16 + col];
            lg[lv] = red32(s) + sw_b[col];
        }
        float mx = fmaxf(fmaxf(lg[0], lg[1]), fmaxf(lg[2], lg[3]));
        float den = 0.f;
#pragma unroll
        for (int lv = 0; lv < 4; lv++){ swv[lv] = expf(lg[lv] - mx); den += swv[lv]; }
        float inv = 1.f / den;
#pragma unroll
        for (int lv = 0; lv < 4; lv++) swv[lv] *= inv;
    }
    float px = bev_pos[qi * 3 + 0] * 100.f - 50.f + off[0];
    float py = bev_pos[qi * 3 + 1] * 100.f - 50.f + off[1];
    float pz = bev_pos[qi * 3 + 2] * 8.f   - 5.f  + off[2];

    float a0 = 0, a1 = 0, a2 = 0, a3 = 0;
    const float* fp[4] = {f0, f1, f2, f3};
    const int HS[4] = {32, 16, 8, 4};
    const int WS[4] = {88, 44, 22, 11};
    for (int cam = 0; cam < 6; cam++){
        const float* M = l2i + cam * 16;
        float t0 = M[0] * px + M[1] * py + M[2]  * pz + M[3];
        float t1 = M[4] * px + M[5] * py + M[6]  * pz + M[7];
        float z  = M[8] * px + M[9] * py + M[10] * pz + M[11];
        float zc = fmaxf(z, 1e-5f);
        float u = t0 / (zc * 704.f);
        float v = t1 / (zc * 256.f);
        if (!((z > 1e-5f) && u >= 0.f && u <= 1.f && v >= 0.f && v <= 1.f)) continue;
#pragma unroll
        for (int l = 0; l < 4; l++){
            const int Hl = HS[l], Wl = WS[l];
            const float* base = fp[l] + (size_t)cam * (Hl * Wl * 128);
            float xx = u * (float)Wl - 0.5f;
            float yy = v * (float)Hl - 0.5f;
            float xf = floorf(xx), yf = floorf(yy);
            float wx = xx - xf, wy = yy - yf;
            int ix = (int)xf, iy = (int)yf;
            float w00 = (1.f - wx) * (1.f - wy);
            float w10 = wx * (1.f - wy);
            float w01 = (1.f - wx) * wy;
            float w11 = wx * wy;
            float s0 = 0, s1 = 0, s2 = 0, s3 = 0;
#pragma unroll
            for (int tap = 0; tap < 4; tap++){
                int tx = ix + (tap & 1);
                int ty = iy + (tap >> 1);
                float w = (tap == 0) ? w00 : (tap == 1) ? w10 : (tap == 2) ? w01 : w11;
                if (tx >= 0 && tx < Wl && ty >= 0 && ty < Hl){
                    float4 vv = *(const float4*)&base[((size_t)ty * Wl + tx) * 128 + d0];
                    s0 += w * vv.x; s1 += w * vv.y; s2 += w * vv.z; s3 += w * vv.w;
                }
            }
            float sl = swv[l];
            a0 += sl * s0; a1 += sl * s1; a2 += sl * s2; a3 += sl * s3;
        }
    }
    ushort4 st; st.x = f2b(a0); st.y = f2b(a1); st.z = f2b(a2); st.w = f2b(a3);
    *(ushort4*)&flat[((size_t)qi * 4 + p) * 128 + d0] = st;
}

// =======================================================================
extern "C" void kernel_launch(void* const* d_in, const int* in_sizes, int n_in,
                              void* d_out, int out_size, void* d_ws, size_t ws_size,
                              hipStream_t stream){
    const float* feat0   = (const float*)d_in[0];
    const float* feat1   = (const float*)d_in[1];
    const float* feat2   = (const float*)d_in[2];
    const float* feat3   = (const float*)d_in[3];
    const float* l2i     = (const float*)d_in[4];
    const float* bev_q   = (const float*)d_in[5];
    const float* bev_pos = (const float*)d_in[6];
    const float* pe_w1   = (const float*)d_in[7];
    const float* pe_b1   = (const float*)d_in[8];
    const float* pe_w2   = (const float*)d_in[9];
    const float* pe_b2   = (const float*)d_in[10];
    const float* conv1_w = (const float*)d_in[11];
    const float* conv1_b = (const float*)d_in[12];
    const float* conv2_w = (const float*)d_in[13];
    const float* conv2_b = (const float*)d_in[14];
    const float* off_w   = (const float*)d_in[15];
    const float* off_b   = (const float*)d_in[16];
    const float* sw_w    = (const float*)d_in[17];
    const float* sw_b    = (const float*)d_in[18];
    const float* cp_w1   = (const float*)d_in[19];
    const float* cp_b1   = (const float*)d_in[20];
    const float* cp_w2   = (const float*)d_in[21];
    const float* cp_b2   = (const float*)d_in[22];
    const float* cp_w3   = (const float*)d_in[23];
    const float* cp_b3   = (const float*)d_in[24];
    const float* ffn_w1  = (const float*)d_in[25];
    const float* ffn_b1  = (const float*)d_in[26];
    const float* ffn_w2  = (const float*)d_in[27];
    const float* ffn_b2  = (const float*)d_in[28];
    const float* n1g = (const float*)d_in[29];
    const float* n1b = (const float*)d_in[30];
    const float* n2g = (const float*)d_in[31];
    const float* n2b = (const float*)d_in[32];
    const float* n3g = (const float*)d_in[33];
    const float* n3b = (const float*)d_in[34];

    // ---- workspace layout (float units) ----
    // pos[5.12M] q[5.12M] bufA[5.12M] bufB[5.12M] featsT[2.87M] flat[bf16 10.24Mf] h1[bf16 10.24Mf]
    float* base = (float*)d_ws;
    float* pos  = base;
    float* qb   = base + 5120000;
    float* bufA = base + 10240000;
    float* bufB = base + 15360000;
    float* ft0  = base + 20480000;
    float* ft1  = ft0 + 6 * 32 * 88 * 128;
    float* ft2  = ft1 + 6 * 16 * 44 * 128;
    float* ft3  = ft2 + 6 * 8 * 22 * 128;
    u16* flat = (u16*)(base + 23352320);
    u16* h1   = (u16*)(base + 33592320);
    float* outp = (float*)d_out;

    // one-time: transpose features to channel-last, position embedding
    transpose_feat<<<(6 * 32 * 88 * 32 + 255) / 256, 256, 0, stream>>>(feat0, ft0, 32, 88);
    transpose_feat<<<(6 * 16 * 44 * 32 + 255) / 256, 256, 0, stream>>>(feat1, ft1, 16, 44);
    transpose_feat<<<(6 * 8 * 22 * 32 + 255) / 256, 256, 0, stream>>>(feat2, ft2, 8, 22);
    transpose_feat<<<(6 * 4 * 11 * 32 + 255) / 256, 256, 0, stream>>>(feat3, ft3, 4, 11);
    pos_embed_kernel<<<5000, 256, 0, stream>>>(bev_pos, pe_w1, pe_b1, pe_w2, pe_b2, pos);

    for (int layer = 0; layer < 2; layer++){
        const float* qin = layer ? qb : bev_q;
        // in_conv: 1x1 GEMM + GELU (input q+pos), then 5x5 conv, then add+LN(n1)
        gemm_kernel<128, 2, true, float, float><<<dim3(625, 1), 256, 0, stream>>>(
            qin, conv1_w, conv1_b, pos, bufA, 128);
        conv5_kernel<<<625, 256, 0, stream>>>(bufA, conv2_w, conv2_b, bufB);
        add_ln_kernel<<<10000, 256, 0, stream>>>(qin, bufB, n1g, n1b, qb);
        // deformable sampling -> flat (bf16)
        sample_kernel<<<20000, 256, 0, stream>>>(qb, bev_pos, l2i, off_w, off_b,
                                                 sw_w, sw_b, ft0, ft1, ft2, ft3, flat);
        // compressor MLP: 512->512 relu, 512->512 relu, 512->128
        gemm_kernel<512, 1, false, u16, u16><<<dim3(625, 4), 256, 0, stream>>>(
            flat, cp_w1, cp_b1, nullptr, h1, 512);
        gemm_kernel<512, 1, false, u16, u16><<<dim3(625, 4), 256, 0, stream>>>(
            h1, cp_w2, cp_b2, nullptr, flat, 512);
        gemm_kernel<512, 0, false, u16, float><<<dim3(625, 1), 256, 0, stream>>>(
            flat, cp_w3, cp_b3, nullptr, bufB, 128);
        add_ln_kernel<<<10000, 256, 0, stream>>>(qb, bufB, n2g, n2b, qb);
        // FFN
        gemm_kernel<128, 1, false, float, float><<<dim3(625, 1), 256, 0, stream>>>(
            qb, ffn_w1, ffn_b1, nullptr, bufA, 128);
        gemm_kernel<128, 0, false, float, float><<<dim3(625, 1), 256, 0, stream>>>(
            bufA, ffn_w2, ffn_b2, nullptr, bufB, 128);
        add_ln_kernel<<<10000, 256, 0, stream>>>(qb, bufB, n3g, n3b, layer ? outp : qb);
    }
}

// Round 2
// 1082.727 us; speedup vs baseline: 3.1412x; 3.1412x over previous
//
#include <hip/hip_runtime.h>
#include <hip/hip_bf16.h>

typedef unsigned short u16;
typedef __attribute__((ext_vector_type(8))) short bf16x8;
typedef __attribute__((ext_vector_type(4))) float f32x4;

#define DEV __device__ __forceinline__

// ---------- bf16 helpers (storage only; math in f32) ----------
DEV float b2f(u16 s){ return __uint_as_float(((unsigned)s) << 16); }
DEV u16 f2b(float f){
    unsigned u = __float_as_uint(f);
    u = u + 0x7fffu + ((u >> 16) & 1u);   // round-to-nearest-even
    return (u16)(u >> 16);
}

DEV float4 loadA4(const float* p){ return *(const float4*)p; }
DEV float4 loadA4(const u16* p){
    ushort4 u = *(const ushort4*)p;
    float4 v; v.x = b2f(u.x); v.y = b2f(u.y); v.z = b2f(u.z); v.w = b2f(u.w);
    return v;
}
DEV void store4(float* p, float a, float b, float c, float d){
    float4 v; v.x = a; v.y = b; v.z = c; v.w = d;
    *(float4*)p = v;
}
DEV void store4(u16* p, float a, float b, float c, float d){
    ushort4 v; v.x = f2b(a); v.y = f2b(b); v.z = f2b(c); v.w = f2b(d);
    *(ushort4*)p = v;
}
DEV void storeElem(float* p, float v){ *p = v; }
DEV void storeElem(u16* p, float v){ *p = f2b(v); }

template<int ACT> DEV float actf(float x){
    if (ACT == 1) return fmaxf(x, 0.f);
    if (ACT == 2) return 0.5f * x * (1.f + erff(x * 0.70710678118654752f)); // exact GELU
    return x;
}

DEV float red32(float v){
    v += __shfl_xor(v, 16, 32);
    v += __shfl_xor(v, 8, 32);
    v += __shfl_xor(v, 4, 32);
    v += __shfl_xor(v, 2, 32);
    v += __shfl_xor(v, 1, 32);
    return v;
}

// async global(16B/lane) -> LDS (wave-uniform base + lane*16)
DEV void gload16(const void* g, void* l){
    __builtin_amdgcn_global_load_lds(
        (const __attribute__((address_space(1))) void*)g,
        (__attribute__((address_space(3))) void*)l, 16, 0, 0);
}

// ---------- feature transpose: (n,C,H,W) -> (n,H,W,C), per level ----------
__global__ void transpose_feat(const float* __restrict__ in, float* __restrict__ out,
                               int H, int W){
    int total = 6 * H * W * 32;                // float4 units
    int lin = blockIdx.x * 256 + threadIdx.x;
    if (lin >= total) return;
    int c4   = (lin & 31) * 4;
    int pix  = lin >> 5;
    int x    = pix % W;
    int rest = pix / W;
    int y    = rest % H;
    int n    = rest / H;
    int HW   = H * W;
    size_t ib = ((size_t)(n * 128 + c4) * H + y) * W + x;
    float4 v;
    v.x = in[ib];
    v.y = in[ib + (size_t)HW];
    v.z = in[ib + (size_t)2 * HW];
    v.w = in[ib + (size_t)3 * HW];
    *(float4*)&out[(size_t)pix * 128 + c4] = v;
}

// ---------- one-time weight prep ----------
// W[K][N] f32 -> WT[N][K] bf16
__global__ void prep_wt(const float* __restrict__ w, u16* __restrict__ o, int K, int N){
    int id = blockIdx.x * 256 + threadIdx.x;
    if (id >= K * N) return;
    int n = id / K, k = id % K;
    o[id] = f2b(w[(size_t)k * N + n]);
}
// conv2_w (5,5,128,128)=[tap][ic][oc] f32 -> per tap, bf16 [oc][ic] pre-swizzled:
// byte = (oc*256 + ic*2) ^ ((oc&7)<<4)
__global__ void prep_conv_w(const float* __restrict__ w, u16* __restrict__ o){
    int id = blockIdx.x * 256 + threadIdx.x;   // 25*128*16 = 51200
    if (id >= 51200) return;
    int slot = id & 15;
    int oc   = (id >> 4) & 127;
    int tap  = id >> 11;
    int ic0  = slot * 8;
    u16 tmp[8];
#pragma unroll
    for (int j = 0; j < 8; j++)
        tmp[j] = f2b(w[((size_t)tap * 128 + ic0 + j) * 128 + oc]);
    int baddr = (oc * 256 + ic0 * 2) ^ ((oc & 7) << 4);
    *(uint4*)((char*)o + (size_t)tap * 32768 + baddr) = *(uint4*)tmp;
}

// ---------- position embedding ----------
__global__ __launch_bounds__(256) void pos_embed_kernel(
    const float* __restrict__ bev_pos,
    const float* __restrict__ w1, const float* __restrict__ b1,
    const float* __restrict__ w2, const float* __restrict__ b2,
    float* __restrict__ pos){
    __shared__ float hid[8][256];
    const int t = threadIdx.x;
    const int q0 = blockIdx.x * 8;
    float wa = w1[t], wb = w1[256 + t], wc = w1[512 + t], bb = b1[t];
#pragma unroll
    for (int qq = 0; qq < 8; qq++){
        float p0 = bev_pos[(q0 + qq) * 3 + 0];
        float p1 = bev_pos[(q0 + qq) * 3 + 1];
        float p2 = bev_pos[(q0 + qq) * 3 + 2];
        hid[qq][t] = fmaxf(p0 * wa + p1 * wb + p2 * wc + bb, 0.f);
    }
    __syncthreads();
    const int oc = t & 127;
    const int qg = (t >> 7) * 4;
    float a0 = 0, a1 = 0, a2 = 0, a3 = 0;
    for (int k = 0; k < 256; k++){
        float w = w2[k * 128 + oc];
        a0 += hid[qg + 0][k] * w;
        a1 += hid[qg + 1][k] * w;
        a2 += hid[qg + 2][k] * w;
        a3 += hid[qg + 3][k] * w;
    }
    float bo = b2[oc];
    pos[(size_t)(q0 + qg + 0) * 128 + oc] = a0 + bo;
    pos[(size_t)(q0 + qg + 1) * 128 + oc] = a1 + bo;
    pos[(size_t)(q0 + qg + 2) * 128 + oc] = a2 + bo;
    pos[(size_t)(q0 + qg + 3) * 128 + oc] = a3 + bo;
}

// ---------- fp32 GEMM (small 128-K ops): C = act(A (+add2) @ W + bias) ----------
template<int K, int ACT, bool ADD2, typename TIN, typename TOUT>
__global__ __launch_bounds__(256) void gemm_kernel(
    const TIN* __restrict__ A, const float* __restrict__ W,
    const float* __restrict__ bias, const float* __restrict__ add2,
    TOUT* __restrict__ C, int Ntot){
    __shared__ float As[64 * 128];
    const int t  = threadIdx.x;
    const int r0 = blockIdx.x * 64;
    const int jb = blockIdx.y * 128;
    const int j0 = (t & 31) * 4;
    const int qg = t >> 5;
    float acc[8][4];
#pragma unroll
    for (int i = 0; i < 8; i++){ acc[i][0] = 0; acc[i][1] = 0; acc[i][2] = 0; acc[i][3] = 0; }

    for (int kc = 0; kc < K; kc += 128){
#pragma unroll
        for (int p = 0; p < 8; p++){
            int lin = p * 256 + t;
            int row = lin >> 5;
            int c4  = (lin & 31) * 4;
            float4 v = loadA4(A + (size_t)(r0 + row) * K + kc + c4);
            if (ADD2){
                float4 w2 = *(const float4*)&add2[(size_t)(r0 + row) * 128 + c4];
                v.x += w2.x; v.y += w2.y; v.z += w2.z; v.w += w2.w;
            }
            *(float4*)&As[row * 128 + c4] = v;
        }
        __syncthreads();
        const float* Wp = W + (size_t)kc * Ntot + jb + j0;
#pragma unroll 4
        for (int k4 = 0; k4 < 128; k4 += 4){
            float4 w0 = *(const float4*)&Wp[(size_t)(k4 + 0) * Ntot];
            float4 w1 = *(const float4*)&Wp[(size_t)(k4 + 1) * Ntot];
            float4 w2 = *(const float4*)&Wp[(size_t)(k4 + 2) * Ntot];
            float4 w3 = *(const float4*)&Wp[(size_t)(k4 + 3) * Ntot];
#pragma unroll
            for (int i = 0; i < 8; i++){
                float4 a = *(const float4*)&As[(qg * 8 + i) * 128 + k4];
                acc[i][0] += a.x * w0.x + a.y * w1.x + a.z * w2.x + a.w * w3.x;
                acc[i][1] += a.x * w0.y + a.y * w1.y + a.z * w2.y + a.w * w3.y;
                acc[i][2] += a.x * w0.z + a.y * w1.z + a.z * w2.z + a.w * w3.z;
                acc[i][3] += a.x * w0.w + a.y * w1.w + a.z * w2.w + a.w * w3.w;
            }
        }
        __syncthreads();
    }
    float4 bv = *(const float4*)&bias[jb + j0];
#pragma unroll
    for (int i = 0; i < 8; i++){
        int r = r0 + qg * 8 + i;
        float o0 = actf<ACT>(acc[i][0] + bv.x);
        float o1 = actf<ACT>(acc[i][1] + bv.y);
        float o2 = actf<ACT>(acc[i][2] + bv.z);
        float o3 = actf<ACT>(acc[i][3] + bv.w);
        store4(C + (size_t)r * Ntot + jb + j0, o0, o1, o2, o3);
    }
}

// ---------- MFMA GEMM: C[M,Ntot] = act(A[M,K]bf16 @ BT[N,K]bf16^T + bias) ----------
// BM=128, BN=128, BK=64; 4 waves, each 64x64 (4x4 frags of 16x16x32).
DEV void stage64(const u16* __restrict__ g, int ldk, u16* lds, int wv, int lane){
    const u16* gp = g + (size_t)(lane >> 3) * ldk + (lane & 7) * 8;
#pragma unroll
    for (int j = 0; j < 4; j++){
        int ch = wv + j * 4;                 // 16 chunks of 1KB (8 rows each)
        gload16(gp + (size_t)ch * 8 * ldk, lds + ch * 512);
    }
}

template<int K, int ACT, typename TOUT>
__global__ __launch_bounds__(256) void mfma_gemm(
    const u16* __restrict__ A, const u16* __restrict__ BT,
    const float* __restrict__ bias, TOUT* __restrict__ C, int Ntot){
    __shared__ u16 As[2][128 * 64];
    __shared__ u16 Bs[2][128 * 64];
    const int t = threadIdx.x, wv = t >> 6, lane = t & 63;
    const int r0 = blockIdx.x * 128, n0 = blockIdx.y * 128;
    const int l15 = lane & 15, kg = lane >> 4;
    const int wr = (wv >> 1) * 64, wc = (wv & 1) * 64;
    f32x4 acc[4][4];
#pragma unroll
    for (int r = 0; r < 4; r++)
#pragma unroll
        for (int c = 0; c < 4; c++) acc[r][c] = (f32x4){0.f, 0.f, 0.f, 0.f};

    stage64(A + (size_t)r0 * K, K, As[0], wv, lane);
    stage64(BT + (size_t)n0 * K, K, Bs[0], wv, lane);
    __syncthreads();
    int buf = 0;
    for (int kc = 0; kc < K / 64; kc++){
        if (kc + 1 < K / 64){
            stage64(A + (size_t)r0 * K + (kc + 1) * 64, K, As[buf ^ 1], wv, lane);
            stage64(BT + (size_t)n0 * K + (kc + 1) * 64, K, Bs[buf ^ 1], wv, lane);
        }
#pragma unroll
        for (int ks = 0; ks < 2; ks++){
            bf16x8 af[4], bfr[4];
#pragma unroll
            for (int r = 0; r < 4; r++)
                af[r] = *(const bf16x8*)&As[buf][(wr + r * 16 + l15) * 64 + ks * 32 + kg * 8];
#pragma unroll
            for (int c = 0; c < 4; c++)
                bfr[c] = *(const bf16x8*)&Bs[buf][(wc + c * 16 + l15) * 64 + ks * 32 + kg * 8];
#pragma unroll
            for (int r = 0; r < 4; r++)
#pragma unroll
                for (int c = 0; c < 4; c++)
                    acc[r][c] = __builtin_amdgcn_mfma_f32_16x16x32_bf16(af[r], bfr[c], acc[r][c], 0, 0, 0);
        }
        __syncthreads();
        buf ^= 1;
    }
#pragma unroll
    for (int c = 0; c < 4; c++){
        int gcol = n0 + wc + c * 16 + l15;
        float bb = bias[gcol];
#pragma unroll
        for (int r = 0; r < 4; r++){
#pragma unroll
            for (int reg = 0; reg < 4; reg++){
                int grow = r0 + wr + r * 16 + kg * 4 + reg;
                storeElem(C + (size_t)grow * Ntot + gcol, actf<ACT>(acc[r][c][reg] + bb));
            }
        }
    }
}

// ---------- 5x5 conv via MFMA implicit GEMM ----------
// block: 8y x 16x pixel tile (M=128) x 128 oc; 4 waves each 64x64.
// Patch 12x20x128 bf16 in LDS (XOR-swizzled); weights streamed per tap (dbuf),
// pre-swizzled in global so linear global_load_lds lands swizzled.
__global__ __launch_bounds__(256) void conv5_mfma(
    const u16* __restrict__ in,     // [200][200][128] bf16
    const u16* __restrict__ wswz,   // [25] x 32KB swizzled [oc][ic] bf16
    const float* __restrict__ bias,
    float* __restrict__ out){       // [200][200][128] f32
    __shared__ u16 Ps[240 * 128];       // 61440 B
    __shared__ u16 Bs[2][128 * 128];    // 2 x 32768 B
    const int t = threadIdx.x, wv = t >> 6, lane = t & 63;
    const int bx = blockIdx.x % 13, by = blockIdx.x / 13;
    const int x0 = bx * 16, y0 = by * 8;
    const int l15 = lane & 15, kg = lane >> 4;
    const int wr = (wv >> 1) * 64, wc = (wv & 1) * 64;

    // patch staging: 240 pixels x 16 slots of 16B, guarded, swizzled
#pragma unroll
    for (int it = 0; it < 15; it++){
        int id = it * 256 + t;
        int pix = id >> 4, slot = id & 15;
        int pr = pix / 20, pc = pix % 20;
        int gy = y0 + pr - 2, gx = x0 + pc - 2;
        uint4 v = {0u, 0u, 0u, 0u};
        if (gy >= 0 && gy < 200 && gx >= 0 && gx < 200)
            v = *(const uint4*)&in[(size_t)(gy * 200 + gx) * 128 + slot * 8];
        int baddr = (pix * 256 + slot * 16) ^ ((pix & 7) << 4);
        *(uint4*)((char*)Ps + baddr) = v;
    }
    // stage tap 0 weights
#pragma unroll
    for (int j = 0; j < 8; j++){
        int ch = wv + j * 4;
        gload16(wswz + ch * 512 + lane * 8, (u16*)Bs[0] + ch * 512);
    }
    f32x4 acc[4][4];
#pragma unroll
    for (int r = 0; r < 4; r++)
#pragma unroll
        for (int c = 0; c < 4; c++) acc[r][c] = (f32x4){0.f, 0.f, 0.f, 0.f};
    __syncthreads();

    int buf = 0;
    for (int tap = 0; tap < 25; tap++){
        if (tap < 24){
            const u16* wt = wswz + (size_t)(tap + 1) * 16384;
#pragma unroll
            for (int j = 0; j < 8; j++){
                int ch = wv + j * 4;
                gload16(wt + ch * 512 + lane * 8, (u16*)Bs[buf ^ 1] + ch * 512);
            }
        }
        const int ky = tap / 5, kx = tap % 5;
#pragma unroll
        for (int ks = 0; ks < 4; ks++){
            bf16x8 af[4], bfr[4];
#pragma unroll
            for (int r = 0; r < 4; r++){
                int py = (wr >> 4) + r;
                int pix = (py + ky) * 20 + kx + l15;
                int baddr = (pix * 256 + ks * 64 + kg * 16) ^ ((pix & 7) << 4);
                af[r] = *(const bf16x8*)((const char*)Ps + baddr);
            }
#pragma unroll
            for (int c = 0; c < 4; c++){
                int oc = wc + c * 16 + l15;
                int baddr = (oc * 256 + ks * 64 + kg * 16) ^ ((oc & 7) << 4);
                bfr[c] = *(const bf16x8*)((const char*)Bs[buf] + baddr);
            }
#pragma unroll
            for (int r = 0; r < 4; r++)
#pragma unroll
                for (int c = 0; c < 4; c++)
                    acc[r][c] = __builtin_amdgcn_mfma_f32_16x16x32_bf16(af[r], bfr[c], acc[r][c], 0, 0, 0);
        }
        __syncthreads();
        buf ^= 1;
    }
#pragma unroll
    for (int c = 0; c < 4; c++){
        int oc = wc + c * 16 + l15;
        float bb = bias[oc];
#pragma unroll
        for (int r = 0; r < 4; r++){
            int py = (wr >> 4) + r;
            int gy = y0 + py;
#pragma unroll
            for (int reg = 0; reg < 4; reg++){
                int px = kg * 4 + reg;
                int gx = x0 + px;
                if (gx < 200)
                    out[(size_t)(gy * 200 + gx) * 128 + oc] = acc[r][c][reg] + bb;
            }
        }
    }
}

// ---------- residual add + LayerNorm over 128, 4 rows/block ----------
__global__ __launch_bounds__(256) void add_ln_kernel(
    const float* __restrict__ a, const float* __restrict__ b,
    const float* __restrict__ gam, const float* __restrict__ bet,
    float* __restrict__ out){
    const int row = blockIdx.x * 4 + (threadIdx.x >> 6);
    const int l   = threadIdx.x & 63;
    const float* pa = a + (size_t)row * 128;
    const float* pb = b + (size_t)row * 128;
    float2 va = *(const float2*)&pa[l * 2];
    float2 vb = *(const float2*)&pb[l * 2];
    float x0 = va.x + vb.x, x1 = va.y + vb.y;
    float s = x0 + x1;
#pragma unroll
    for (int m = 32; m >= 1; m >>= 1) s += __shfl_xor(s, m, 64);
    float mean = s * 0.0078125f;
    float e0 = x0 - mean, e1 = x1 - mean;
    float v = e0 * e0 + e1 * e1;
#pragma unroll
    for (int m = 32; m >= 1; m >>= 1) v += __shfl_xor(v, m, 64);
    float rs = rsqrtf(v * 0.0078125f + 1e-5f);
    float2 vg = *(const float2*)&gam[l * 2];
    float2 vt = *(const float2*)&bet[l * 2];
    float2 o;
    o.x = e0 * rs * vg.x + vt.x;
    o.y = e1 * rs * vg.y + vt.y;
    *(float2*)&out[(size_t)row * 128 + l * 2] = o;
}

// ---------- deformable sampling: q -> flat(Q, P*128) bf16 ----------
__global__ __launch_bounds__(256) void sample_kernel(
    const float* __restrict__ q, const float* __restrict__ bev_pos,
    const float* __restrict__ l2i,
    const float* __restrict__ off_w, const float* __restrict__ off_b,
    const float* __restrict__ sw_w, const float* __restrict__ sw_b,
    const float* __restrict__ f0, const float* __restrict__ f1,
    const float* __restrict__ f2, const float* __restrict__ f3,
    u16* __restrict__ flat){
    const int t = threadIdx.x;
    const int lane = t & 31;
    const int p = (t >> 5) & 3;
    const int qi = blockIdx.x * 2 + (t >> 7);
    const int d0 = lane * 4;
    float4 qv = *(const float4*)&q[(size_t)qi * 128 + d0];

    float off[3];
#pragma unroll
    for (int k = 0; k < 3; k++){
        int col = p * 3 + k;
        float s = qv.x * off_w[(d0 + 0) * 12 + col] + qv.y * off_w[(d0 + 1) * 12 + col]
                + qv.z * off_w[(d0 + 2) * 12 + col] + qv.w * off_w[(d0 + 3) * 12 + col];
        off[k] = red32(s) + off_b[col];
    }
    float swv[4];
    {
        float lg[4];
#pragma unroll
        for (int lv = 0; lv < 4; lv++){
            int col = p * 4 + lv;
            float s = qv.x * sw_w[(d0 + 0) * 16 + col] + qv.y * sw_w[(d0 + 1) * 16 + col]
                    + qv.z * sw_w[(d0 + 2) * 16 + col] + qv.w * sw_w[(d0 + 3) * 16 + col];
            lg[lv] = red32(s) + sw_b[col];
        }
        float mx = fmaxf(fmaxf(lg[0], lg[1]), fmaxf(lg[2], lg[3]));
        float den = 0.f;
#pragma unroll
        for (int lv = 0; lv < 4; lv++){ swv[lv] = expf(lg[lv] - mx); den += swv[lv]; }
        float inv = 1.f / den;
#pragma unroll
        for (int lv = 0; lv < 4; lv++) swv[lv] *= inv;
    }
    float px = bev_pos[qi * 3 + 0] * 100.f - 50.f + off[0];
    float py = bev_pos[qi * 3 + 1] * 100.f - 50.f + off[1];
    float pz = bev_pos[qi * 3 + 2] * 8.f   - 5.f  + off[2];

    float a0 = 0, a1 = 0, a2 = 0, a3 = 0;
    const float* fp[4] = {f0, f1, f2, f3};
    const int HS[4] = {32, 16, 8, 4};
    const int WS[4] = {88, 44, 22, 11};
    for (int cam = 0; cam < 6; cam++){
        const float* M = l2i + cam * 16;
        float t0 = M[0] * px + M[1] * py + M[2]  * pz + M[3];
        float t1 = M[4] * px + M[5] * py + M[6]  * pz + M[7];
        float z  = M[8] * px + M[9] * py + M[10] * pz + M[11];
        float zc = fmaxf(z, 1e-5f);
        float u = t0 / (zc * 704.f);
        float v = t1 / (zc * 256.f);
        if (!((z > 1e-5f) && u >= 0.f && u <= 1.f && v >= 0.f && v <= 1.f)) continue;
#pragma unroll
        for (int l = 0; l < 4; l++){
            const int Hl = HS[l], Wl = WS[l];
            const float* base = fp[l] + (size_t)cam * (Hl * Wl * 128);
            float xx = u * (float)Wl - 0.5f;
            float yy = v * (float)Hl - 0.5f;
            float xf = floorf(xx), yf = floorf(yy);
            float wx = xx - xf, wy = yy - yf;
            int ix = (int)xf, iy = (int)yf;
            float w00 = (1.f - wx) * (1.f - wy);
            float w10 = wx * (1.f - wy);
            float w01 = (1.f - wx) * wy;
            float w11 = wx * wy;
            float s0 = 0, s1 = 0, s2 = 0, s3 = 0;
#pragma unroll
            for (int tap = 0; tap < 4; tap++){
                int tx = ix + (tap & 1);
                int ty = iy + (tap >> 1);
                float w = (tap == 0) ? w00 : (tap == 1) ? w10 : (tap == 2) ? w01 : w11;
                if (tx >= 0 && tx < Wl && ty >= 0 && ty < Hl){
                    float4 vv = *(const float4*)&base[((size_t)ty * Wl + tx) * 128 + d0];
                    s0 += w * vv.x; s1 += w * vv.y; s2 += w * vv.z; s3 += w * vv.w;
                }
            }
            float sl = swv[l];
            a0 += sl * s0; a1 += sl * s1; a2 += sl * s2; a3 += sl * s3;
        }
    }
    ushort4 st; st.x = f2b(a0); st.y = f2b(a1); st.z = f2b(a2); st.w = f2b(a3);
    *(ushort4*)&flat[((size_t)qi * 4 + p) * 128 + d0] = st;
}

// =======================================================================
extern "C" void kernel_launch(void* const* d_in, const int* in_sizes, int n_in,
                              void* d_out, int out_size, void* d_ws, size_t ws_size,
                              hipStream_t stream){
    const float* feat0   = (const float*)d_in[0];
    const float* feat1   = (const float*)d_in[1];
    const float* feat2   = (const float*)d_in[2];
    const float* feat3   = (const float*)d_in[3];
    const float* l2i     = (const float*)d_in[4];
    const float* bev_q   = (const float*)d_in[5];
    const float* bev_pos = (const float*)d_in[6];
    const float* pe_w1   = (const float*)d_in[7];
    const float* pe_b1   = (const float*)d_in[8];
    const float* pe_w2   = (const float*)d_in[9];
    const float* pe_b2   = (const float*)d_in[10];
    const float* conv1_w = (const float*)d_in[11];
    const float* conv1_b = (const float*)d_in[12];
    const float* conv2_w = (const float*)d_in[13];
    const float* conv2_b = (const float*)d_in[14];
    const float* off_w   = (const float*)d_in[15];
    const float* off_b   = (const float*)d_in[16];
    const float* sw_w    = (const float*)d_in[17];
    const float* sw_b    = (const float*)d_in[18];
    const float* cp_w1   = (const float*)d_in[19];
    const float* cp_b1   = (const float*)d_in[20];
    const float* cp_w2   = (const float*)d_in[21];
    const float* cp_b2   = (const float*)d_in[22];
    const float* cp_w3   = (const float*)d_in[23];
    const float* cp_b3   = (const float*)d_in[24];
    const float* ffn_w1  = (const float*)d_in[25];
    const float* ffn_b1  = (const float*)d_in[26];
    const float* ffn_w2  = (const float*)d_in[27];
    const float* ffn_b2  = (const float*)d_in[28];
    const float* n1g = (const float*)d_in[29];
    const float* n1b = (const float*)d_in[30];
    const float* n2g = (const float*)d_in[31];
    const float* n2b = (const float*)d_in[32];
    const float* n3g = (const float*)d_in[33];
    const float* n3b = (const float*)d_in[34];

    // ---- workspace layout (float units) ----
    float* base = (float*)d_ws;
    float* pos   = base;                                   // 5,120,000
    float* qb    = base + 5120000;                         // 5,120,000
    float* bufB  = base + 10240000;                        // 5,128,192 (40064x128 f32)
    u16*   bufA16= (u16*)(base + 15368192);                // 40000x128 bf16
    u16*   flat  = (u16*)(base + 17928192);                // 40064x512 bf16
    u16*   h1    = (u16*)(base + 28184576);                // 40064x512 bf16
    float* ft0   = base + 38440960;
    float* ft1   = ft0 + 6 * 32 * 88 * 128;
    float* ft2   = ft1 + 6 * 16 * 44 * 128;
    float* ft3   = ft2 + 6 * 8 * 22 * 128;
    u16*   w1t   = (u16*)(base + 41313280);                // [512][512]
    u16*   w2t   = (u16*)(base + 41444352);                // [512][512]
    u16*   w3t   = (u16*)(base + 41575424);                // [128][512]
    u16*   wcs   = (u16*)(base + 41608192);                // 25 x 32KB swizzled
    float* ffnbuf= (float*)flat;                           // reuse (free at FFN time)
    float* outp  = (float*)d_out;

    // one-time prep
    transpose_feat<<<(6 * 32 * 88 * 32 + 255) / 256, 256, 0, stream>>>(feat0, ft0, 32, 88);
    transpose_feat<<<(6 * 16 * 44 * 32 + 255) / 256, 256, 0, stream>>>(feat1, ft1, 16, 44);
    transpose_feat<<<(6 * 8 * 22 * 32 + 255) / 256, 256, 0, stream>>>(feat2, ft2, 8, 22);
    transpose_feat<<<(6 * 4 * 11 * 32 + 255) / 256, 256, 0, stream>>>(feat3, ft3, 4, 11);
    pos_embed_kernel<<<5000, 256, 0, stream>>>(bev_pos, pe_w1, pe_b1, pe_w2, pe_b2, pos);
    prep_wt<<<(512 * 512 + 255) / 256, 256, 0, stream>>>(cp_w1, w1t, 512, 512);
    prep_wt<<<(512 * 512 + 255) / 256, 256, 0, stream>>>(cp_w2, w2t, 512, 512);
    prep_wt<<<(512 * 128 + 255) / 256, 256, 0, stream>>>(cp_w3, w3t, 512, 128);
    prep_conv_w<<<(51200 + 255) / 256, 256, 0, stream>>>(conv2_w, wcs);

    for (int layer = 0; layer < 2; layer++){
        const float* qin = layer ? qb : bev_q;
        // in_conv: 1x1 GEMM + GELU (q+pos) -> bf16, then 5x5 MFMA conv, then add+LN
        gemm_kernel<128, 2, true, float, u16><<<dim3(625, 1), 256, 0, stream>>>(
            qin, conv1_w, conv1_b, pos, bufA16, 128);
        conv5_mfma<<<25 * 13, 256, 0, stream>>>(bufA16, wcs, conv2_b, bufB);
        add_ln_kernel<<<10000, 256, 0, stream>>>(qin, bufB, n1g, n1b, qb);
        // deformable sampling -> flat (bf16)
        sample_kernel<<<20000, 256, 0, stream>>>(qb, bev_pos, l2i, off_w, off_b,
                                                 sw_w, sw_b, ft0, ft1, ft2, ft3, flat);
        // compressor MLP (MFMA): 512->512 relu, 512->512 relu, 512->128
        mfma_gemm<512, 1, u16><<<dim3(313, 4), 256, 0, stream>>>(flat, w1t, cp_b1, h1, 512);
        mfma_gemm<512, 1, u16><<<dim3(313, 4), 256, 0, stream>>>(h1, w2t, cp_b2, flat, 512);
        mfma_gemm<512, 0, float><<<dim3(313, 1), 256, 0, stream>>>(flat, w3t, cp_b3, bufB, 128);
        add_ln_kernel<<<10000, 256, 0, stream>>>(qb, bufB, n2g, n2b, qb);
        // FFN (fp32)
        gemm_kernel<128, 1, false, float, float><<<dim3(625, 1), 256, 0, stream>>>(
            qb, ffn_w1, ffn_b1, nullptr, ffnbuf, 128);
        gemm_kernel<128, 0, false, float, float><<<dim3(625, 1), 256, 0, stream>>>(
            ffnbuf, ffn_w2, ffn_b2, nullptr, bufB, 128);
        add_ln_kernel<<<10000, 256, 0, stream>>>(qb, bufB, n3g, n3b, layer ? outp : qb);
    }
}

// Round 3
// 769.622 us; speedup vs baseline: 4.4192x; 1.4068x over previous
//
#include <hip/hip_runtime.h>
#include <hip/hip_bf16.h>

typedef unsigned short u16;
typedef __attribute__((ext_vector_type(8))) short bf16x8;
typedef __attribute__((ext_vector_type(4))) float f32x4;

#define DEV __device__ __forceinline__

// ---------- bf16 helpers (storage only; math in f32) ----------
DEV float b2f(u16 s){ return __uint_as_float(((unsigned)s) << 16); }
DEV u16 f2b(float f){
    unsigned u = __float_as_uint(f);
    u = u + 0x7fffu + ((u >> 16) & 1u);   // round-to-nearest-even
    return (u16)(u >> 16);
}
DEV void storeElem(float* p, float v){ *p = v; }
DEV void storeElem(u16* p, float v){ *p = f2b(v); }

template<int ACT> DEV float actf(float x){
    if (ACT == 1) return fmaxf(x, 0.f);
    if (ACT == 2) return 0.5f * x * (1.f + erff(x * 0.70710678118654752f)); // exact GELU
    return x;
}

// async global(16B/lane) -> LDS (wave-uniform base + lane*16)
DEV void gload16(const void* g, void* l){
    __builtin_amdgcn_global_load_lds(
        (const __attribute__((address_space(1))) void*)g,
        (__attribute__((address_space(3))) void*)l, 16, 0, 0);
}

// ---------- feature transpose: (n,C,H,W) f32 -> (n,H,W,C) bf16 ----------
__global__ void transpose_feat(const float* __restrict__ in, u16* __restrict__ out,
                               int H, int W){
    int total = 6 * H * W * 32;                // float4 units
    int lin = blockIdx.x * 256 + threadIdx.x;
    if (lin >= total) return;
    int c4   = (lin & 31) * 4;
    int pix  = lin >> 5;
    int x    = pix % W;
    int rest = pix / W;
    int y    = rest % H;
    int n    = rest / H;
    int HW   = H * W;
    size_t ib = ((size_t)(n * 128 + c4) * H + y) * W + x;
    ushort4 v;
    v.x = f2b(in[ib]);
    v.y = f2b(in[ib + (size_t)HW]);
    v.z = f2b(in[ib + (size_t)2 * HW]);
    v.w = f2b(in[ib + (size_t)3 * HW]);
    *(ushort4*)&out[(size_t)pix * 128 + c4] = v;
}

// ---------- one-time weight prep ----------
// W[K][N] f32 -> WT[N][K] bf16
__global__ void prep_wt(const float* __restrict__ w, u16* __restrict__ o, int K, int N){
    int id = blockIdx.x * 256 + threadIdx.x;
    if (id >= K * N) return;
    int n = id / K, k = id % K;
    o[id] = f2b(w[(size_t)k * N + n]);
}
// combined off/sw weight: owsT[32][128], obias[32]
__global__ void prep_osw_w(const float* __restrict__ off_w, const float* __restrict__ off_b,
                           const float* __restrict__ sw_w, const float* __restrict__ sw_b,
                           u16* __restrict__ owsT, float* __restrict__ obias){
    int id = blockIdx.x * 256 + threadIdx.x;   // 32*128 = 4096
    if (id >= 4096) return;
    int n = id >> 7, k = id & 127;
    float w = (n < 12) ? off_w[k * 12 + n] : (n < 28) ? sw_w[k * 16 + (n - 12)] : 0.f;
    owsT[n * 128 + k] = f2b(w);
    if (k == 0) obias[n] = (n < 12) ? off_b[n] : (n < 28) ? sw_b[n - 12] : 0.f;
}
// conv2_w (5,5,128,128)=[tap][ic][oc] f32 -> per tap, bf16 [oc][ic] pre-swizzled
__global__ void prep_conv_w(const float* __restrict__ w, u16* __restrict__ o){
    int id = blockIdx.x * 256 + threadIdx.x;   // 25*128*16 = 51200
    if (id >= 51200) return;
    int slot = id & 15;
    int oc   = (id >> 4) & 127;
    int tap  = id >> 11;
    int ic0  = slot * 8;
    u16 tmp[8];
#pragma unroll
    for (int j = 0; j < 8; j++)
        tmp[j] = f2b(w[((size_t)tap * 128 + ic0 + j) * 128 + oc]);
    int baddr = (oc * 256 + ic0 * 2) ^ ((oc & 7) << 4);
    *(uint4*)((char*)o + (size_t)tap * 32768 + baddr) = *(uint4*)tmp;
}
// qpos16 = bf16(bev_q + pos), 4 elems/thread
__global__ void prep_qpos(const float* __restrict__ q, const float* __restrict__ pos,
                          u16* __restrict__ o){
    int i4 = blockIdx.x * 256 + threadIdx.x;    // 1,280,000 total
    if (i4 >= 1280000) return;
    const float4 a = *(const float4*)&q[(size_t)i4 * 4];
    const float4 p = *(const float4*)&pos[(size_t)i4 * 4];
    ushort4 v; v.x = f2b(a.x + p.x); v.y = f2b(a.y + p.y);
    v.z = f2b(a.z + p.z); v.w = f2b(a.w + p.w);
    *(ushort4*)&o[(size_t)i4 * 4] = v;
}

// ---------- position embedding ----------
__global__ __launch_bounds__(256) void pos_embed_kernel(
    const float* __restrict__ bev_pos,
    const float* __restrict__ w1, const float* __restrict__ b1,
    const float* __restrict__ w2, const float* __restrict__ b2,
    float* __restrict__ pos){
    __shared__ float hid[8][256];
    const int t = threadIdx.x;
    const int q0 = blockIdx.x * 8;
    float wa = w1[t], wb = w1[256 + t], wc = w1[512 + t], bb = b1[t];
#pragma unroll
    for (int qq = 0; qq < 8; qq++){
        float p0 = bev_pos[(q0 + qq) * 3 + 0];
        float p1 = bev_pos[(q0 + qq) * 3 + 1];
        float p2 = bev_pos[(q0 + qq) * 3 + 2];
        hid[qq][t] = fmaxf(p0 * wa + p1 * wb + p2 * wc + bb, 0.f);
    }
    __syncthreads();
    const int oc = t & 127;
    const int qg = (t >> 7) * 4;
    float a0 = 0, a1 = 0, a2 = 0, a3 = 0;
    for (int k = 0; k < 256; k++){
        float w = w2[k * 128 + oc];
        a0 += hid[qg + 0][k] * w;
        a1 += hid[qg + 1][k] * w;
        a2 += hid[qg + 2][k] * w;
        a3 += hid[qg + 3][k] * w;
    }
    float bo = b2[oc];
    pos[(size_t)(q0 + qg + 0) * 128 + oc] = a0 + bo;
    pos[(size_t)(q0 + qg + 1) * 128 + oc] = a1 + bo;
    pos[(size_t)(q0 + qg + 2) * 128 + oc] = a2 + bo;
    pos[(size_t)(q0 + qg + 3) * 128 + oc] = a3 + bo;
}

// ---------- MFMA GEMM: C[M,Ntot] = act(A[M,K]bf16 @ BT[N,K]^T + bias) ----------
DEV void stage64(const u16* __restrict__ g, int ldk, u16* lds, int wv, int lane){
    const u16* gp = g + (size_t)(lane >> 3) * ldk + (lane & 7) * 8;
#pragma unroll
    for (int j = 0; j < 4; j++){
        int ch = wv + j * 4;                 // 16 chunks of 1KB (8 rows each)
        gload16(gp + (size_t)ch * 8 * ldk, lds + ch * 512);
    }
}

template<int K, int ACT, typename TOUT>
__global__ __launch_bounds__(256) void mfma_gemm(
    const u16* __restrict__ A, const u16* __restrict__ BT,
    const float* __restrict__ bias, TOUT* __restrict__ C, int Ntot){
    __shared__ u16 As[2][128 * 64];
    __shared__ u16 Bs[2][128 * 64];
    const int t = threadIdx.x, wv = t >> 6, lane = t & 63;
    const int r0 = blockIdx.x * 128, n0 = blockIdx.y * 128;
    const int l15 = lane & 15, kg = lane >> 4;
    const int wr = (wv >> 1) * 64, wc = (wv & 1) * 64;
    f32x4 acc[4][4];
#pragma unroll
    for (int r = 0; r < 4; r++)
#pragma unroll
        for (int c = 0; c < 4; c++) acc[r][c] = (f32x4){0.f, 0.f, 0.f, 0.f};

    stage64(A + (size_t)r0 * K, K, As[0], wv, lane);
    stage64(BT + (size_t)n0 * K, K, Bs[0], wv, lane);
    __syncthreads();
    int buf = 0;
    for (int kc = 0; kc < K / 64; kc++){
        if (kc + 1 < K / 64){
            stage64(A + (size_t)r0 * K + (kc + 1) * 64, K, As[buf ^ 1], wv, lane);
            stage64(BT + (size_t)n0 * K + (kc + 1) * 64, K, Bs[buf ^ 1], wv, lane);
        }
#pragma unroll
        for (int ks = 0; ks < 2; ks++){
            bf16x8 af[4], bfr[4];
#pragma unroll
            for (int r = 0; r < 4; r++)
                af[r] = *(const bf16x8*)&As[buf][(wr + r * 16 + l15) * 64 + ks * 32 + kg * 8];
#pragma unroll
            for (int c = 0; c < 4; c++)
                bfr[c] = *(const bf16x8*)&Bs[buf][(wc + c * 16 + l15) * 64 + ks * 32 + kg * 8];
#pragma unroll
            for (int r = 0; r < 4; r++)
#pragma unroll
                for (int c = 0; c < 4; c++)
                    acc[r][c] = __builtin_amdgcn_mfma_f32_16x16x32_bf16(af[r], bfr[c], acc[r][c], 0, 0, 0);
        }
        __syncthreads();
        buf ^= 1;
    }
#pragma unroll
    for (int c = 0; c < 4; c++){
        int gcol = n0 + wc + c * 16 + l15;
        float bb = bias[gcol];
#pragma unroll
        for (int r = 0; r < 4; r++){
#pragma unroll
            for (int reg = 0; reg < 4; reg++){
                int grow = r0 + wr + r * 16 + kg * 4 + reg;
                storeElem(C + (size_t)grow * Ntot + gcol, actf<ACT>(acc[r][c][reg] + bb));
            }
        }
    }
}

// ---------- small MFMA GEMM: osw[M][32] = q16[M][128] @ owsT[32][128]^T + obias ----------
__global__ __launch_bounds__(256) void mfma_osw(
    const u16* __restrict__ A, const u16* __restrict__ BT,
    const float* __restrict__ bias, float* __restrict__ osw){
    __shared__ u16 As[2][128 * 64];   // [k-half][row*64 + k']
    __shared__ u16 Bs[2][32 * 64];
    const int t = threadIdx.x, wv = t >> 6, lane = t & 63;
    const int r0 = blockIdx.x * 128;
    const int l15 = lane & 15, kg = lane >> 4;
#pragma unroll
    for (int it = 0; it < 8; it++){
        int id = it * 256 + t;
        int row = id >> 4, slot = id & 15;
        uint4 v = *(const uint4*)&A[(size_t)(r0 + row) * 128 + slot * 8];
        *(uint4*)&As[slot >> 3][row * 64 + (slot & 7) * 8] = v;
    }
#pragma unroll
    for (int it = 0; it < 2; it++){
        int id = it * 256 + t;
        if (id < 512){
            int row = id >> 4, slot = id & 15;
            uint4 v = *(const uint4*)&BT[(size_t)row * 128 + slot * 8];
            *(uint4*)&Bs[slot >> 3][row * 64 + (slot & 7) * 8] = v;
        }
    }
    __syncthreads();
    f32x4 acc[2][2];
#pragma unroll
    for (int r = 0; r < 2; r++)
#pragma unroll
        for (int c = 0; c < 2; c++) acc[r][c] = (f32x4){0.f, 0.f, 0.f, 0.f};
#pragma unroll
    for (int ks = 0; ks < 4; ks++){
        int h = ks >> 1, koff = (ks & 1) * 32 + kg * 8;
        bf16x8 af[2], bfr[2];
#pragma unroll
        for (int r = 0; r < 2; r++)
            af[r] = *(const bf16x8*)&As[h][(wv * 32 + r * 16 + l15) * 64 + koff];
#pragma unroll
        for (int c = 0; c < 2; c++)
            bfr[c] = *(const bf16x8*)&Bs[h][(c * 16 + l15) * 64 + koff];
#pragma unroll
        for (int r = 0; r < 2; r++)
#pragma unroll
            for (int c = 0; c < 2; c++)
                acc[r][c] = __builtin_amdgcn_mfma_f32_16x16x32_bf16(af[r], bfr[c], acc[r][c], 0, 0, 0);
    }
#pragma unroll
    for (int c = 0; c < 2; c++){
        int gcol = c * 16 + l15;
        float bb = bias[gcol];
#pragma unroll
        for (int r = 0; r < 2; r++)
#pragma unroll
            for (int reg = 0; reg < 4; reg++){
                int grow = r0 + wv * 32 + r * 16 + kg * 4 + reg;
                osw[(size_t)grow * 32 + gcol] = acc[r][c][reg] + bb;
            }
    }
}

// ---------- projection: per (q,p): softmax(sw) + 6 cam (u,v) w/ -1 sentinel ----------
__global__ __launch_bounds__(256) void proj_kernel(
    const float* __restrict__ osw, const float* __restrict__ bev_pos,
    const float* __restrict__ l2i, float* __restrict__ swuv){
    int id = blockIdx.x * 256 + threadIdx.x;   // 160000 total
    int qi = id >> 2, p = id & 3;
    const float* row = osw + (size_t)qi * 32;
    float px = bev_pos[qi * 3 + 0] * 100.f - 50.f + row[p * 3 + 0];
    float py = bev_pos[qi * 3 + 1] * 100.f - 50.f + row[p * 3 + 1];
    float pz = bev_pos[qi * 3 + 2] * 8.f   - 5.f  + row[p * 3 + 2];
    float lg[4];
#pragma unroll
    for (int l = 0; l < 4; l++) lg[l] = row[12 + p * 4 + l];
    float mx = fmaxf(fmaxf(lg[0], lg[1]), fmaxf(lg[2], lg[3]));
    float den = 0.f, sw[4];
#pragma unroll
    for (int l = 0; l < 4; l++){ sw[l] = expf(lg[l] - mx); den += sw[l]; }
    float inv = 1.f / den;
    float4 o0; o0.x = sw[0] * inv; o0.y = sw[1] * inv; o0.z = sw[2] * inv; o0.w = sw[3] * inv;
    float uv[12];
#pragma unroll
    for (int cam = 0; cam < 6; cam++){
        const float* M = l2i + cam * 16;
        float t0 = M[0] * px + M[1] * py + M[2]  * pz + M[3];
        float t1 = M[4] * px + M[5] * py + M[6]  * pz + M[7];
        float z  = M[8] * px + M[9] * py + M[10] * pz + M[11];
        float zc = fmaxf(z, 1e-5f);
        float u = t0 / (zc * 704.f);
        float v = t1 / (zc * 256.f);
        bool ok = (z > 1e-5f) && u >= 0.f && u <= 1.f && v >= 0.f && v <= 1.f;
        uv[cam * 2 + 0] = ok ? u : -1.f;
        uv[cam * 2 + 1] = ok ? v : 0.f;
    }
    float* out = swuv + (size_t)id * 16;
    *(float4*)&out[0]  = o0;
    *(float4*)&out[4]  = *(float4*)&uv[0];
    *(float4*)&out[8]  = *(float4*)&uv[4];
    *(float4*)&out[12] = *(float4*)&uv[8];
}

// ---------- deformable sampling: pure gather. 16 lanes/(q,p), 8 ch/lane ----------
__global__ __launch_bounds__(256) void sample_kernel(
    const float* __restrict__ swuv,
    const u16* __restrict__ f0, const u16* __restrict__ f1,
    const u16* __restrict__ f2, const u16* __restrict__ f3,
    u16* __restrict__ flat){
    const int t = threadIdx.x;
    const int lane = t & 15;
    const int id = blockIdx.x * 16 + (t >> 4);
    const int d0 = lane * 8;
    const float* sp = swuv + (size_t)id * 16;
    float4 sw = *(const float4*)sp;
    float swl[4] = {sw.x, sw.y, sw.z, sw.w};
    float acc[8] = {0, 0, 0, 0, 0, 0, 0, 0};
    const int HS[4] = {32, 16, 8, 4};
    const int WS[4] = {88, 44, 22, 11};
#pragma unroll
    for (int cam = 0; cam < 6; cam++){
        float u = sp[4 + cam * 2], v = sp[5 + cam * 2];
        if (u < 0.f) continue;
#pragma unroll
        for (int l = 0; l < 4; l++){
            const int Hl = HS[l], Wl = WS[l];
            const u16* fb = (l == 0 ? f0 : l == 1 ? f1 : l == 2 ? f2 : f3)
                          + (size_t)cam * (Hl * Wl * 128);
            float xx = u * (float)Wl - 0.5f;
            float yy = v * (float)Hl - 0.5f;
            float xf = floorf(xx), yf = floorf(yy);
            float wx = xx - xf, wy = yy - yf;
            int ix = (int)xf, iy = (int)yf;
            float sl = swl[l];
            float cw[4];
            cw[0] = sl * (1.f - wx) * (1.f - wy);
            cw[1] = sl * wx * (1.f - wy);
            cw[2] = sl * (1.f - wx) * wy;
            cw[3] = sl * wx * wy;
#pragma unroll
            for (int tap = 0; tap < 4; tap++){
                int tx = ix + (tap & 1);
                int ty = iy + (tap >> 1);
                if ((unsigned)tx < (unsigned)Wl && (unsigned)ty < (unsigned)Hl){
                    uint4 vv = *(const uint4*)&fb[(size_t)(ty * Wl + tx) * 128 + d0];
                    float w = cw[tap];
                    acc[0] += w * __uint_as_float(vv.x << 16);
                    acc[1] += w * __uint_as_float(vv.x & 0xffff0000u);
                    acc[2] += w * __uint_as_float(vv.y << 16);
                    acc[3] += w * __uint_as_float(vv.y & 0xffff0000u);
                    acc[4] += w * __uint_as_float(vv.z << 16);
                    acc[5] += w * __uint_as_float(vv.z & 0xffff0000u);
                    acc[6] += w * __uint_as_float(vv.w << 16);
                    acc[7] += w * __uint_as_float(vv.w & 0xffff0000u);
                }
            }
        }
    }
    uint4 o;
    o.x = (unsigned)f2b(acc[0]) | ((unsigned)f2b(acc[1]) << 16);
    o.y = (unsigned)f2b(acc[2]) | ((unsigned)f2b(acc[3]) << 16);
    o.z = (unsigned)f2b(acc[4]) | ((unsigned)f2b(acc[5]) << 16);
    o.w = (unsigned)f2b(acc[6]) | ((unsigned)f2b(acc[7]) << 16);
    *(uint4*)&flat[(size_t)id * 128 + d0] = o;
}

// ---------- 5x5 conv via MFMA implicit GEMM ----------
__global__ __launch_bounds__(256) void conv5_mfma(
    const u16* __restrict__ in,     // [200][200][128] bf16
    const u16* __restrict__ wswz,   // [25] x 32KB swizzled [oc][ic] bf16
    const float* __restrict__ bias,
    float* __restrict__ out){       // [200][200][128] f32
    __shared__ u16 Ps[240 * 128];       // 61440 B
    __shared__ u16 Bs[2][128 * 128];    // 2 x 32768 B
    const int t = threadIdx.x, wv = t >> 6, lane = t & 63;
    const int bx = blockIdx.x % 13, by = blockIdx.x / 13;
    const int x0 = bx * 16, y0 = by * 8;
    const int l15 = lane & 15, kg = lane >> 4;
    const int wr = (wv >> 1) * 64, wc = (wv & 1) * 64;
#pragma unroll
    for (int it = 0; it < 15; it++){
        int id = it * 256 + t;
        int pix = id >> 4, slot = id & 15;
        int pr = pix / 20, pc = pix % 20;
        int gy = y0 + pr - 2, gx = x0 + pc - 2;
        uint4 v = {0u, 0u, 0u, 0u};
        if (gy >= 0 && gy < 200 && gx >= 0 && gx < 200)
            v = *(const uint4*)&in[(size_t)(gy * 200 + gx) * 128 + slot * 8];
        int baddr = (pix * 256 + slot * 16) ^ ((pix & 7) << 4);
        *(uint4*)((char*)Ps + baddr) = v;
    }
#pragma unroll
    for (int j = 0; j < 8; j++){
        int ch = wv + j * 4;
        gload16(wswz + ch * 512 + lane * 8, (u16*)Bs[0] + ch * 512);
    }
    f32x4 acc[4][4];
#pragma unroll
    for (int r = 0; r < 4; r++)
#pragma unroll
        for (int c = 0; c < 4; c++) acc[r][c] = (f32x4){0.f, 0.f, 0.f, 0.f};
    __syncthreads();

    int buf = 0;
    for (int tap = 0; tap < 25; tap++){
        if (tap < 24){
            const u16* wt = wswz + (size_t)(tap + 1) * 16384;
#pragma unroll
            for (int j = 0; j < 8; j++){
                int ch = wv + j * 4;
                gload16(wt + ch * 512 + lane * 8, (u16*)Bs[buf ^ 1] + ch * 512);
            }
        }
        const int ky = tap / 5, kx = tap % 5;
#pragma unroll
        for (int ks = 0; ks < 4; ks++){
            bf16x8 af[4], bfr[4];
#pragma unroll
            for (int r = 0; r < 4; r++){
                int py = (wr >> 4) + r;
                int pix = (py + ky) * 20 + kx + l15;
                int baddr = (pix * 256 + ks * 64 + kg * 16) ^ ((pix & 7) << 4);
                af[r] = *(const bf16x8*)((const char*)Ps + baddr);
            }
#pragma unroll
            for (int c = 0; c < 4; c++){
                int oc = wc + c * 16 + l15;
                int baddr = (oc * 256 + ks * 64 + kg * 16) ^ ((oc & 7) << 4);
                bfr[c] = *(const bf16x8*)((const char*)Bs[buf] + baddr);
            }
#pragma unroll
            for (int r = 0; r < 4; r++)
#pragma unroll
                for (int c = 0; c < 4; c++)
                    acc[r][c] = __builtin_amdgcn_mfma_f32_16x16x32_bf16(af[r], bfr[c], acc[r][c], 0, 0, 0);
        }
        __syncthreads();
        buf ^= 1;
    }
#pragma unroll
    for (int c = 0; c < 4; c++){
        int oc = wc + c * 16 + l15;
        float bb = bias[oc];
#pragma unroll
        for (int r = 0; r < 4; r++){
            int py = (wr >> 4) + r;
            int gy = y0 + py;
#pragma unroll
            for (int reg = 0; reg < 4; reg++){
                int px = kg * 4 + reg;
                int gx = x0 + px;
                if (gx < 200)
                    out[(size_t)(gy * 200 + gx) * 128 + oc] = acc[r][c][reg] + bb;
            }
        }
    }
}

// ---------- residual add + LayerNorm (MODE: 0 none, 1 aux=bf16(out), 2 aux=bf16(out+pos)) ----------
template<int MODE>
__global__ __launch_bounds__(256) void add_ln_kernel(
    const float* __restrict__ a, const float* __restrict__ b,
    const float* __restrict__ gam, const float* __restrict__ bet,
    float* __restrict__ out, u16* __restrict__ aux, const float* __restrict__ pos){
    const int row = blockIdx.x * 4 + (threadIdx.x >> 6);
    const int l   = threadIdx.x & 63;
    const float* pa = a + (size_t)row * 128;
    const float* pb = b + (size_t)row * 128;
    float2 va = *(const float2*)&pa[l * 2];
    float2 vb = *(const float2*)&pb[l * 2];
    float x0 = va.x + vb.x, x1 = va.y + vb.y;
    float s = x0 + x1;
#pragma unroll
    for (int m = 32; m >= 1; m >>= 1) s += __shfl_xor(s, m, 64);
    float mean = s * 0.0078125f;
    float e0 = x0 - mean, e1 = x1 - mean;
    float v = e0 * e0 + e1 * e1;
#pragma unroll
    for (int m = 32; m >= 1; m >>= 1) v += __shfl_xor(v, m, 64);
    float rs = rsqrtf(v * 0.0078125f + 1e-5f);
    float2 vg = *(const float2*)&gam[l * 2];
    float2 vt = *(const float2*)&bet[l * 2];
    float2 o;
    o.x = e0 * rs * vg.x + vt.x;
    o.y = e1 * rs * vg.y + vt.y;
    *(float2*)&out[(size_t)row * 128 + l * 2] = o;
    if (MODE == 1){
        ushort2 h; h.x = f2b(o.x); h.y = f2b(o.y);
        *(ushort2*)&aux[(size_t)row * 128 + l * 2] = h;
    } else if (MODE == 2){
        float2 pp = *(const float2*)&pos[(size_t)row * 128 + l * 2];
        ushort2 h; h.x = f2b(o.x + pp.x); h.y = f2b(o.y + pp.y);
        *(ushort2*)&aux[(size_t)row * 128 + l * 2] = h;
    }
}

// =======================================================================
extern "C" void kernel_launch(void* const* d_in, const int* in_sizes, int n_in,
                              void* d_out, int out_size, void* d_ws, size_t ws_size,
                              hipStream_t stream){
    const float* feat0   = (const float*)d_in[0];
    const float* feat1   = (const float*)d_in[1];
    const float* feat2   = (const float*)d_in[2];
    const float* feat3   = (const float*)d_in[3];
    const float* l2i     = (const float*)d_in[4];
    const float* bev_q   = (const float*)d_in[5];
    const float* bev_pos = (const float*)d_in[6];
    const float* pe_w1   = (const float*)d_in[7];
    const float* pe_b1   = (const float*)d_in[8];
    const float* pe_w2   = (const float*)d_in[9];
    const float* pe_b2   = (const float*)d_in[10];
    const float* conv1_w = (const float*)d_in[11];
    const float* conv1_b = (const float*)d_in[12];
    const float* conv2_w = (const float*)d_in[13];
    const float* conv2_b = (const float*)d_in[14];
    const float* off_w   = (const float*)d_in[15];
    const float* off_b   = (const float*)d_in[16];
    const float* sw_w    = (const float*)d_in[17];
    const float* sw_b    = (const float*)d_in[18];
    const float* cp_w1   = (const float*)d_in[19];
    const float* cp_b1   = (const float*)d_in[20];
    const float* cp_w2   = (const float*)d_in[21];
    const float* cp_b2   = (const float*)d_in[22];
    const float* cp_w3   = (const float*)d_in[23];
    const float* cp_b3   = (const float*)d_in[24];
    const float* ffn_w1  = (const float*)d_in[25];
    const float* ffn_b1  = (const float*)d_in[26];
    const float* ffn_w2  = (const float*)d_in[27];
    const float* ffn_b2  = (const float*)d_in[28];
    const float* n1g = (const float*)d_in[29];
    const float* n1b = (const float*)d_in[30];
    const float* n2g = (const float*)d_in[31];
    const float* n2b = (const float*)d_in[32];
    const float* n3g = (const float*)d_in[33];
    const float* n3b = (const float*)d_in[34];

    // ---- workspace layout (float units) ----
    float* base   = (float*)d_ws;
    float* pos    = base;                                  //  5,128,192
    float* qb     = base + 5128192;                        //  5,128,192
    float* hbuf   = base + 10256384;                       // 10,256,384 (h1 full; bufB = first half)
    float* bufB   = hbuf;
    u16*   h1     = (u16*)hbuf;
    u16*   q16    = (u16*)(base + 20512768);               //  2,564,096
    u16*   qpos16 = (u16*)(base + 23076864);               //  2,564,096 (aliased: swuv)
    float* swuv   = (float*)qpos16;
    u16*   bufA16 = (u16*)(base + 25640960);               //  2,564,096 (aliased: osw)
    float* osw    = (float*)bufA16;
    u16*   flat   = (u16*)(base + 28205056);               // 10,256,384
    u16*   ft0    = (u16*)(base + 38461440);
    u16*   ft1    = ft0 + 6 * 32 * 88 * 128;
    u16*   ft2    = ft1 + 6 * 16 * 44 * 128;
    u16*   ft3    = ft2 + 6 * 8 * 22 * 128;
    u16*   w1t    = (u16*)(base + 39897600);               // [512][512]
    u16*   w2t    = (u16*)(base + 40028672);
    u16*   w3t    = (u16*)(base + 40159744);               // [128][512]
    u16*   wc1t   = (u16*)(base + 40192512);               // [128][128]
    u16*   wf1t   = (u16*)(base + 40200704);
    u16*   wf2t   = (u16*)(base + 40208896);
    u16*   owsT   = (u16*)(base + 40217088);               // [32][128]
    float* obias  = (float*)(base + 40219136);             // 32
    u16*   wcs    = (u16*)(base + 40219168);               // 25 x 32KB swizzled
    float* outp   = (float*)d_out;

    // one-time prep
    transpose_feat<<<(6 * 32 * 88 * 32 + 255) / 256, 256, 0, stream>>>(feat0, ft0, 32, 88);
    transpose_feat<<<(6 * 16 * 44 * 32 + 255) / 256, 256, 0, stream>>>(feat1, ft1, 16, 44);
    transpose_feat<<<(6 * 8 * 22 * 32 + 255) / 256, 256, 0, stream>>>(feat2, ft2, 8, 22);
    transpose_feat<<<(6 * 4 * 11 * 32 + 255) / 256, 256, 0, stream>>>(feat3, ft3, 4, 11);
    pos_embed_kernel<<<5000, 256, 0, stream>>>(bev_pos, pe_w1, pe_b1, pe_w2, pe_b2, pos);
    prep_wt<<<(512 * 512 + 255) / 256, 256, 0, stream>>>(cp_w1, w1t, 512, 512);
    prep_wt<<<(512 * 512 + 255) / 256, 256, 0, stream>>>(cp_w2, w2t, 512, 512);
    prep_wt<<<(512 * 128 + 255) / 256, 256, 0, stream>>>(cp_w3, w3t, 512, 128);
    prep_wt<<<(128 * 128 + 255) / 256, 256, 0, stream>>>(conv1_w, wc1t, 128, 128);
    prep_wt<<<(128 * 128 + 255) / 256, 256, 0, stream>>>(ffn_w1, wf1t, 128, 128);
    prep_wt<<<(128 * 128 + 255) / 256, 256, 0, stream>>>(ffn_w2, wf2t, 128, 128);
    prep_osw_w<<<16, 256, 0, stream>>>(off_w, off_b, sw_w, sw_b, owsT, obias);
    prep_conv_w<<<(51200 + 255) / 256, 256, 0, stream>>>(conv2_w, wcs);
    prep_qpos<<<5000, 256, 0, stream>>>(bev_q, pos, qpos16);

    for (int layer = 0; layer < 2; layer++){
        const float* qin = layer ? qb : bev_q;
        // in_conv: 1x1 MFMA GEMM + GELU -> bf16, then 5x5 MFMA conv, then add+LN(n1)+aux bf16
        mfma_gemm<128, 2, u16><<<dim3(313, 1), 256, 0, stream>>>(qpos16, wc1t, conv1_b, bufA16, 128);
        conv5_mfma<<<25 * 13, 256, 0, stream>>>(bufA16, wcs, conv2_b, bufB);
        add_ln_kernel<1><<<10000, 256, 0, stream>>>(qin, bufB, n1g, n1b, qb, q16, nullptr);
        // off/sw GEMM -> proj -> sampling
        mfma_osw<<<313, 256, 0, stream>>>(q16, owsT, obias, osw);
        proj_kernel<<<625, 256, 0, stream>>>(osw, bev_pos, l2i, swuv);
        sample_kernel<<<10000, 256, 0, stream>>>(swuv, ft0, ft1, ft2, ft3, flat);
        // compressor MLP (MFMA): 512->512 relu, 512->512 relu, 512->128
        mfma_gemm<512, 1, u16><<<dim3(313, 4), 256, 0, stream>>>(flat, w1t, cp_b1, h1, 512);
        mfma_gemm<512, 1, u16><<<dim3(313, 4), 256, 0, stream>>>(h1, w2t, cp_b2, flat, 512);
        mfma_gemm<512, 0, float><<<dim3(313, 1), 256, 0, stream>>>(flat, w3t, cp_b3, bufB, 128);
        add_ln_kernel<1><<<10000, 256, 0, stream>>>(qb, bufB, n2g, n2b, qb, q16, nullptr);
        // FFN (MFMA)
        mfma_gemm<128, 1, u16><<<dim3(313, 1), 256, 0, stream>>>(q16, wf1t, ffn_b1, bufA16, 128);
        mfma_gemm<128, 0, float><<<dim3(313, 1), 256, 0, stream>>>(bufA16, wf2t, ffn_b2, bufB, 128);
        if (layer == 0)
            add_ln_kernel<2><<<10000, 256, 0, stream>>>(qb, bufB, n3g, n3b, qb, qpos16, pos);
        else
            add_ln_kernel<0><<<10000, 256, 0, stream>>>(qb, bufB, n3g, n3b, outp, nullptr, nullptr);
    }
}

// Round 4
// 731.081 us; speedup vs baseline: 4.6521x; 1.0527x over previous
//
#include <hip/hip_runtime.h>
#include <hip/hip_bf16.h>

typedef unsigned short u16;
typedef __attribute__((ext_vector_type(8))) short bf16x8;
typedef __attribute__((ext_vector_type(4))) float f32x4;

#define DEV __device__ __forceinline__

// ---------- bf16 helpers (storage only; math in f32) ----------
DEV float b2f(u16 s){ return __uint_as_float(((unsigned)s) << 16); }
DEV u16 f2b(float f){
    unsigned u = __float_as_uint(f);
    u = u + 0x7fffu + ((u >> 16) & 1u);   // round-to-nearest-even
    return (u16)(u >> 16);
}
DEV void storeElem(float* p, float v){ *p = v; }
DEV void storeElem(u16* p, float v){ *p = f2b(v); }

template<int ACT> DEV float actf(float x){
    if (ACT == 1) return fmaxf(x, 0.f);
    if (ACT == 2) return 0.5f * x * (1.f + erff(x * 0.70710678118654752f)); // exact GELU
    return x;
}

// async global(16B/lane) -> LDS (wave-uniform base + lane*16)
DEV void gload16(const void* g, void* l){
    __builtin_amdgcn_global_load_lds(
        (const __attribute__((address_space(1))) void*)g,
        (__attribute__((address_space(3))) void*)l, 16, 0, 0);
}

// ---------- feature transpose: (n,C,H,W) f32 -> (n,H,W,C) bf16 ----------
__global__ void transpose_feat(const float* __restrict__ in, u16* __restrict__ out,
                               int H, int W){
    int total = 6 * H * W * 32;                // float4 units
    int lin = blockIdx.x * 256 + threadIdx.x;
    if (lin >= total) return;
    int c4   = (lin & 31) * 4;
    int pix  = lin >> 5;
    int x    = pix % W;
    int rest = pix / W;
    int y    = rest % H;
    int n    = rest / H;
    int HW   = H * W;
    size_t ib = ((size_t)(n * 128 + c4) * H + y) * W + x;
    ushort4 v;
    v.x = f2b(in[ib]);
    v.y = f2b(in[ib + (size_t)HW]);
    v.z = f2b(in[ib + (size_t)2 * HW]);
    v.w = f2b(in[ib + (size_t)3 * HW]);
    *(ushort4*)&out[(size_t)pix * 128 + c4] = v;
}

// ---------- one-time weight prep ----------
// W[K][N] f32 -> WT[N][K] bf16
__global__ void prep_wt(const float* __restrict__ w, u16* __restrict__ o, int K, int N){
    int id = blockIdx.x * 256 + threadIdx.x;
    if (id >= K * N) return;
    int n = id / K, k = id % K;
    o[id] = f2b(w[(size_t)k * N + n]);
}
// combined off/sw weight: owsT[32][128], obias[32]
__global__ void prep_osw_w(const float* __restrict__ off_w, const float* __restrict__ off_b,
                           const float* __restrict__ sw_w, const float* __restrict__ sw_b,
                           u16* __restrict__ owsT, float* __restrict__ obias){
    int id = blockIdx.x * 256 + threadIdx.x;   // 32*128 = 4096
    if (id >= 4096) return;
    int n = id >> 7, k = id & 127;
    float w = (n < 12) ? off_w[k * 12 + n] : (n < 28) ? sw_w[k * 16 + (n - 12)] : 0.f;
    owsT[n * 128 + k] = f2b(w);
    if (k == 0) obias[n] = (n < 12) ? off_b[n] : (n < 28) ? sw_b[n - 12] : 0.f;
}
// conv2_w (5,5,128,128)=[tap][ic][oc] f32 -> per tap, bf16 [oc][ic] pre-swizzled:
// byte = oc*256 + ((slot ^ (oc&15))<<4), slot = ic0/8
__global__ void prep_conv_w(const float* __restrict__ w, u16* __restrict__ o){
    int id = blockIdx.x * 256 + threadIdx.x;   // 25*128*16 = 51200
    if (id >= 51200) return;
    int slot = id & 15;
    int oc   = (id >> 4) & 127;
    int tap  = id >> 11;
    int ic0  = slot * 8;
    u16 tmp[8];
#pragma unroll
    for (int j = 0; j < 8; j++)
        tmp[j] = f2b(w[((size_t)tap * 128 + ic0 + j) * 128 + oc]);
    int baddr = oc * 256 + ((slot ^ (oc & 15)) << 4);
    *(uint4*)((char*)o + (size_t)tap * 32768 + baddr) = *(uint4*)tmp;
}
// qpos16 = bf16(bev_q + pos), 4 elems/thread
__global__ void prep_qpos(const float* __restrict__ q, const float* __restrict__ pos,
                          u16* __restrict__ o){
    int i4 = blockIdx.x * 256 + threadIdx.x;    // 1,280,000 total
    if (i4 >= 1280000) return;
    const float4 a = *(const float4*)&q[(size_t)i4 * 4];
    const float4 p = *(const float4*)&pos[(size_t)i4 * 4];
    ushort4 v; v.x = f2b(a.x + p.x); v.y = f2b(a.y + p.y);
    v.z = f2b(a.z + p.z); v.w = f2b(a.w + p.w);
    *(ushort4*)&o[(size_t)i4 * 4] = v;
}

// ---------- position embedding ----------
__global__ __launch_bounds__(256) void pos_embed_kernel(
    const float* __restrict__ bev_pos,
    const float* __restrict__ w1, const float* __restrict__ b1,
    const float* __restrict__ w2, const float* __restrict__ b2,
    float* __restrict__ pos){
    __shared__ float hid[8][256];
    const int t = threadIdx.x;
    const int q0 = blockIdx.x * 8;
    float wa = w1[t], wb = w1[256 + t], wc = w1[512 + t], bb = b1[t];
#pragma unroll
    for (int qq = 0; qq < 8; qq++){
        float p0 = bev_pos[(q0 + qq) * 3 + 0];
        float p1 = bev_pos[(q0 + qq) * 3 + 1];
        float p2 = bev_pos[(q0 + qq) * 3 + 2];
        hid[qq][t] = fmaxf(p0 * wa + p1 * wb + p2 * wc + bb, 0.f);
    }
    __syncthreads();
    const int oc = t & 127;
    const int qg = (t >> 7) * 4;
    float a0 = 0, a1 = 0, a2 = 0, a3 = 0;
    for (int k = 0; k < 256; k++){
        float w = w2[k * 128 + oc];
        a0 += hid[qg + 0][k] * w;
        a1 += hid[qg + 1][k] * w;
        a2 += hid[qg + 2][k] * w;
        a3 += hid[qg + 3][k] * w;
    }
    float bo = b2[oc];
    pos[(size_t)(q0 + qg + 0) * 128 + oc] = a0 + bo;
    pos[(size_t)(q0 + qg + 1) * 128 + oc] = a1 + bo;
    pos[(size_t)(q0 + qg + 2) * 128 + oc] = a2 + bo;
    pos[(size_t)(q0 + qg + 3) * 128 + oc] = a3 + bo;
}

// ---------- MFMA GEMM: C[M,Ntot] = act(A[M,K]bf16 @ BT[N,K]^T + bias) ----------
DEV void stage64(const u16* __restrict__ g, int ldk, u16* lds, int wv, int lane){
    const u16* gp = g + (size_t)(lane >> 3) * ldk + (lane & 7) * 8;
#pragma unroll
    for (int j = 0; j < 4; j++){
        int ch = wv + j * 4;                 // 16 chunks of 1KB (8 rows each)
        gload16(gp + (size_t)ch * 8 * ldk, lds + ch * 512);
    }
}

template<int K, int ACT, typename TOUT>
__global__ __launch_bounds__(256) void mfma_gemm(
    const u16* __restrict__ A, const u16* __restrict__ BT,
    const float* __restrict__ bias, TOUT* __restrict__ C, int Ntot){
    __shared__ u16 As[2][128 * 64];
    __shared__ u16 Bs[2][128 * 64];
    const int t = threadIdx.x, wv = t >> 6, lane = t & 63;
    const int r0 = blockIdx.x * 128, n0 = blockIdx.y * 128;
    const int l15 = lane & 15, kg = lane >> 4;
    const int wr = (wv >> 1) * 64, wc = (wv & 1) * 64;
    f32x4 acc[4][4];
#pragma unroll
    for (int r = 0; r < 4; r++)
#pragma unroll
        for (int c = 0; c < 4; c++) acc[r][c] = (f32x4){0.f, 0.f, 0.f, 0.f};

    stage64(A + (size_t)r0 * K, K, As[0], wv, lane);
    stage64(BT + (size_t)n0 * K, K, Bs[0], wv, lane);
    __syncthreads();
    int buf = 0;
    for (int kc = 0; kc < K / 64; kc++){
        if (kc + 1 < K / 64){
            stage64(A + (size_t)r0 * K + (kc + 1) * 64, K, As[buf ^ 1], wv, lane);
            stage64(BT + (size_t)n0 * K + (kc + 1) * 64, K, Bs[buf ^ 1], wv, lane);
        }
#pragma unroll
        for (int ks = 0; ks < 2; ks++){
            bf16x8 af[4], bfr[4];
#pragma unroll
            for (int r = 0; r < 4; r++)
                af[r] = *(const bf16x8*)&As[buf][(wr + r * 16 + l15) * 64 + ks * 32 + kg * 8];
#pragma unroll
            for (int c = 0; c < 4; c++)
                bfr[c] = *(const bf16x8*)&Bs[buf][(wc + c * 16 + l15) * 64 + ks * 32 + kg * 8];
#pragma unroll
            for (int r = 0; r < 4; r++)
#pragma unroll
                for (int c = 0; c < 4; c++)
                    acc[r][c] = __builtin_amdgcn_mfma_f32_16x16x32_bf16(af[r], bfr[c], acc[r][c], 0, 0, 0);
        }
        __syncthreads();
        buf ^= 1;
    }
#pragma unroll
    for (int c = 0; c < 4; c++){
        int gcol = n0 + wc + c * 16 + l15;
        float bb = bias[gcol];
#pragma unroll
        for (int r = 0; r < 4; r++){
#pragma unroll
            for (int reg = 0; reg < 4; reg++){
                int grow = r0 + wr + r * 16 + kg * 4 + reg;
                storeElem(C + (size_t)grow * Ntot + gcol, actf<ACT>(acc[r][c][reg] + bb));
            }
        }
    }
}

// ---------- small MFMA GEMM: osw[M][32] = q16[M][128] @ owsT[32][128]^T + obias ----------
__global__ __launch_bounds__(256) void mfma_osw(
    const u16* __restrict__ A, const u16* __restrict__ BT,
    const float* __restrict__ bias, float* __restrict__ osw){
    __shared__ u16 As[2][128 * 64];   // [k-half][row*64 + k']
    __shared__ u16 Bs[2][32 * 64];
    const int t = threadIdx.x, wv = t >> 6, lane = t & 63;
    const int r0 = blockIdx.x * 128;
    const int l15 = lane & 15, kg = lane >> 4;
#pragma unroll
    for (int it = 0; it < 8; it++){
        int id = it * 256 + t;
        int row = id >> 4, slot = id & 15;
        uint4 v = *(const uint4*)&A[(size_t)(r0 + row) * 128 + slot * 8];
        *(uint4*)&As[slot >> 3][row * 64 + (slot & 7) * 8] = v;
    }
#pragma unroll
    for (int it = 0; it < 2; it++){
        int id = it * 256 + t;
        if (id < 512){
            int row = id >> 4, slot = id & 15;
            uint4 v = *(const uint4*)&BT[(size_t)row * 128 + slot * 8];
            *(uint4*)&Bs[slot >> 3][row * 64 + (slot & 7) * 8] = v;
        }
    }
    __syncthreads();
    f32x4 acc[2][2];
#pragma unroll
    for (int r = 0; r < 2; r++)
#pragma unroll
        for (int c = 0; c < 2; c++) acc[r][c] = (f32x4){0.f, 0.f, 0.f, 0.f};
#pragma unroll
    for (int ks = 0; ks < 4; ks++){
        int h = ks >> 1, koff = (ks & 1) * 32 + kg * 8;
        bf16x8 af[2], bfr[2];
#pragma unroll
        for (int r = 0; r < 2; r++)
            af[r] = *(const bf16x8*)&As[h][(wv * 32 + r * 16 + l15) * 64 + koff];
#pragma unroll
        for (int c = 0; c < 2; c++)
            bfr[c] = *(const bf16x8*)&Bs[h][(c * 16 + l15) * 64 + koff];
#pragma unroll
        for (int r = 0; r < 2; r++)
#pragma unroll
            for (int c = 0; c < 2; c++)
                acc[r][c] = __builtin_amdgcn_mfma_f32_16x16x32_bf16(af[r], bfr[c], acc[r][c], 0, 0, 0);
    }
#pragma unroll
    for (int c = 0; c < 2; c++){
        int gcol = c * 16 + l15;
        float bb = bias[gcol];
#pragma unroll
        for (int r = 0; r < 2; r++)
#pragma unroll
            for (int reg = 0; reg < 4; reg++){
                int grow = r0 + wv * 32 + r * 16 + kg * 4 + reg;
                osw[(size_t)grow * 32 + gcol] = acc[r][c][reg] + bb;
            }
    }
}

// ---------- projection: per (q,p): softmax(sw) + 6 cam (u,v) w/ -1 sentinel ----------
__global__ __launch_bounds__(256) void proj_kernel(
    const float* __restrict__ osw, const float* __restrict__ bev_pos,
    const float* __restrict__ l2i, float* __restrict__ swuv){
    int id = blockIdx.x * 256 + threadIdx.x;   // 160000 total
    int qi = id >> 2, p = id & 3;
    const float* row = osw + (size_t)qi * 32;
    float px = bev_pos[qi * 3 + 0] * 100.f - 50.f + row[p * 3 + 0];
    float py = bev_pos[qi * 3 + 1] * 100.f - 50.f + row[p * 3 + 1];
    float pz = bev_pos[qi * 3 + 2] * 8.f   - 5.f  + row[p * 3 + 2];
    float lg[4];
#pragma unroll
    for (int l = 0; l < 4; l++) lg[l] = row[12 + p * 4 + l];
    float mx = fmaxf(fmaxf(lg[0], lg[1]), fmaxf(lg[2], lg[3]));
    float den = 0.f, sw[4];
#pragma unroll
    for (int l = 0; l < 4; l++){ sw[l] = expf(lg[l] - mx); den += sw[l]; }
    float inv = 1.f / den;
    float4 o0; o0.x = sw[0] * inv; o0.y = sw[1] * inv; o0.z = sw[2] * inv; o0.w = sw[3] * inv;
    float uv[12];
#pragma unroll
    for (int cam = 0; cam < 6; cam++){
        const float* M = l2i + cam * 16;
        float t0 = M[0] * px + M[1] * py + M[2]  * pz + M[3];
        float t1 = M[4] * px + M[5] * py + M[6]  * pz + M[7];
        float z  = M[8] * px + M[9] * py + M[10] * pz + M[11];
        float zc = fmaxf(z, 1e-5f);
        float u = t0 / (zc * 704.f);
        float v = t1 / (zc * 256.f);
        bool ok = (z > 1e-5f) && u >= 0.f && u <= 1.f && v >= 0.f && v <= 1.f;
        uv[cam * 2 + 0] = ok ? u : -1.f;
        uv[cam * 2 + 1] = ok ? v : 0.f;
    }
    float* out = swuv + (size_t)id * 16;
    *(float4*)&out[0]  = o0;
    *(float4*)&out[4]  = *(float4*)&uv[0];
    *(float4*)&out[8]  = *(float4*)&uv[4];
    *(float4*)&out[12] = *(float4*)&uv[8];
}

// ---------- deformable sampling: branchless taps. 16 lanes/(q,p), 8 ch/lane ----------
DEV void fma8(float* acc, uint4 v, float w){
    acc[0] = fmaf(__uint_as_float(v.x << 16), w, acc[0]);
    acc[1] = fmaf(__uint_as_float(v.x & 0xffff0000u), w, acc[1]);
    acc[2] = fmaf(__uint_as_float(v.y << 16), w, acc[2]);
    acc[3] = fmaf(__uint_as_float(v.y & 0xffff0000u), w, acc[3]);
    acc[4] = fmaf(__uint_as_float(v.z << 16), w, acc[4]);
    acc[5] = fmaf(__uint_as_float(v.z & 0xffff0000u), w, acc[5]);
    acc[6] = fmaf(__uint_as_float(v.w << 16), w, acc[6]);
    acc[7] = fmaf(__uint_as_float(v.w & 0xffff0000u), w, acc[7]);
}

__global__ __launch_bounds__(256) void sample_kernel(
    const float* __restrict__ swuv,
    const u16* __restrict__ f0, const u16* __restrict__ f1,
    const u16* __restrict__ f2, const u16* __restrict__ f3,
    u16* __restrict__ flat){
    const int t = threadIdx.x;
    const int lane = t & 15;
    const int id = blockIdx.x * 16 + (t >> 4);
    const int d0 = lane * 8;
    const float* sp = swuv + (size_t)id * 16;
    float4 sw = *(const float4*)sp;
    float swl[4] = {sw.x, sw.y, sw.z, sw.w};
    float acc[8] = {0, 0, 0, 0, 0, 0, 0, 0};
    const int HS[4] = {32, 16, 8, 4};
    const int WS[4] = {88, 44, 22, 11};
#pragma unroll
    for (int cam = 0; cam < 6; cam++){
        float u = sp[4 + cam * 2], v = sp[5 + cam * 2];
        if (u < 0.f) continue;
#pragma unroll
        for (int l = 0; l < 4; l++){
            const int Hl = HS[l], Wl = WS[l];
            const u16* fb = (l == 0 ? f0 : l == 1 ? f1 : l == 2 ? f2 : f3)
                          + (size_t)cam * (Hl * Wl * 128) + d0;
            float xx = u * (float)Wl - 0.5f;
            float yy = v * (float)Hl - 0.5f;
            float xf = floorf(xx), yf = floorf(yy);
            float wx = xx - xf, wy = yy - yf;
            int ix = (int)xf, iy = (int)yf;
            float sl = swl[l];
            float wx0 = (ix >= 0)      ? 1.f - wx : 0.f;
            float wx1 = (ix < Wl - 1)  ? wx       : 0.f;
            float wy0 = (iy >= 0)      ? 1.f - wy : 0.f;
            float wy1 = (iy < Hl - 1)  ? wy       : 0.f;
            int x0c = max(ix, 0), x1c = min(ix + 1, Wl - 1);
            int y0c = max(iy, 0), y1c = min(iy + 1, Hl - 1);
            const u16* r0p = fb + (size_t)(y0c * Wl) * 128;
            const u16* r1p = fb + (size_t)(y1c * Wl) * 128;
            uint4 v00 = *(const uint4*)(r0p + (size_t)x0c * 128);
            uint4 v10 = *(const uint4*)(r0p + (size_t)x1c * 128);
            uint4 v01 = *(const uint4*)(r1p + (size_t)x0c * 128);
            uint4 v11 = *(const uint4*)(r1p + (size_t)x1c * 128);
            fma8(acc, v00, sl * wx0 * wy0);
            fma8(acc, v10, sl * wx1 * wy0);
            fma8(acc, v01, sl * wx0 * wy1);
            fma8(acc, v11, sl * wx1 * wy1);
        }
    }
    uint4 o;
    o.x = (unsigned)f2b(acc[0]) | ((unsigned)f2b(acc[1]) << 16);
    o.y = (unsigned)f2b(acc[2]) | ((unsigned)f2b(acc[3]) << 16);
    o.z = (unsigned)f2b(acc[4]) | ((unsigned)f2b(acc[5]) << 16);
    o.w = (unsigned)f2b(acc[6]) | ((unsigned)f2b(acc[7]) << 16);
    *(uint4*)&flat[(size_t)id * 128 + d0] = o;
}

// ---------- 5x5 conv via MFMA implicit GEMM ----------
// 512 threads = 8 waves (2 M-halves x 4 N-quarters). Tile: 160 px (10y x 16x) x 128 oc.
// Grid 20x13 = 260 blocks (~1 round on 256 CUs). Patch 14x20x128 bf16 + weight dbuf.
// Conflict-free LDS: byte = row*256 + ((slot ^ (row&15))<<4).
__global__ __launch_bounds__(512) void conv5_mfma(
    const u16* __restrict__ in,     // [200][200][128] bf16
    const u16* __restrict__ wswz,   // [25] x 32KB pre-swizzled [oc][ic] bf16
    const float* __restrict__ bias,
    float* __restrict__ out){       // [200][200][128] f32
    __shared__ u16 Ps[280 * 128];       // 71680 B
    __shared__ u16 Bs[2][128 * 128];    // 2 x 32768 B
    const int t = threadIdx.x, wv = t >> 6, lane = t & 63;
    const int bx = blockIdx.x % 13, by = blockIdx.x / 13;
    const int x0 = bx * 16, y0 = by * 10;
    const int l15 = lane & 15, kg = lane >> 4;
    const int wr = (wv >> 2) * 80, wc = (wv & 3) * 32;
    const int pyb = (wv >> 2) * 5;

    // patch staging: 280 pixels x 16 slots of 16B, guarded, swizzled
#pragma unroll
    for (int it = 0; it < 9; it++){
        int id = it * 512 + t;
        if (id < 4480){
            int pix = id >> 4, slot = id & 15;
            int pr = pix / 20, pc = pix % 20;
            int gy = y0 + pr - 2, gx = x0 + pc - 2;
            uint4 v = {0u, 0u, 0u, 0u};
            if (gy >= 0 && gy < 200 && gx >= 0 && gx < 200)
                v = *(const uint4*)&in[(size_t)(gy * 200 + gx) * 128 + slot * 8];
            int baddr = pix * 256 + ((slot ^ (pix & 15)) << 4);
            *(uint4*)((char*)Ps + baddr) = v;
        }
    }
    // stage tap 0 weights (32 chunks of 1KB, 4 per wave)
#pragma unroll
    for (int j = 0; j < 4; j++){
        int ch = wv * 4 + j;
        gload16(wswz + ch * 512 + lane * 8, (u16*)Bs[0] + ch * 512);
    }
    f32x4 acc[5][2];
#pragma unroll
    for (int r = 0; r < 5; r++)
#pragma unroll
        for (int c = 0; c < 2; c++) acc[r][c] = (f32x4){0.f, 0.f, 0.f, 0.f};
    __syncthreads();

    int buf = 0;
    for (int tap = 0; tap < 25; tap++){
        if (tap < 24){
            const u16* wt = wswz + (size_t)(tap + 1) * 16384;
#pragma unroll
            for (int j = 0; j < 4; j++){
                int ch = wv * 4 + j;
                gload16(wt + ch * 512 + lane * 8, (u16*)Bs[buf ^ 1] + ch * 512);
            }
        }
        const int ky = tap / 5, kx = tap % 5;
#pragma unroll
        for (int ks = 0; ks < 4; ks++){
            const int slot = ks * 4 + kg;
            bf16x8 af[5], bfr[2];
#pragma unroll
            for (int r = 0; r < 5; r++){
                int pix = (pyb + r + ky) * 20 + kx + l15;
                int baddr = pix * 256 + ((slot ^ (pix & 15)) << 4);
                af[r] = *(const bf16x8*)((const char*)Ps + baddr);
            }
#pragma unroll
            for (int c = 0; c < 2; c++){
                int oc = wc + c * 16 + l15;
                int baddr = oc * 256 + ((slot ^ (oc & 15)) << 4);
                bfr[c] = *(const bf16x8*)((const char*)Bs[buf] + baddr);
            }
#pragma unroll
            for (int r = 0; r < 5; r++)
#pragma unroll
                for (int c = 0; c < 2; c++)
                    acc[r][c] = __builtin_amdgcn_mfma_f32_16x16x32_bf16(af[r], bfr[c], acc[r][c], 0, 0, 0);
        }
        __syncthreads();
        buf ^= 1;
    }
#pragma unroll
    for (int c = 0; c < 2; c++){
        int oc = wc + c * 16 + l15;
        float bb = bias[oc];
#pragma unroll
        for (int r = 0; r < 5; r++){
#pragma unroll
            for (int reg = 0; reg < 4; reg++){
                int m = wr + r * 16 + kg * 4 + reg;
                int py = m >> 4, px = m & 15;
                int gx = x0 + px;
                if (gx < 200)
                    out[(size_t)((y0 + py) * 200 + gx) * 128 + oc] = acc[r][c][reg] + bb;
            }
        }
    }
}

// ---------- residual add + LayerNorm (MODE: 0 none, 1 aux=bf16(out), 2 aux=bf16(out+pos)) ----------
template<int MODE>
__global__ __launch_bounds__(256) void add_ln_kernel(
    const float* __restrict__ a, const float* __restrict__ b,
    const float* __restrict__ gam, const float* __restrict__ bet,
    float* __restrict__ out, u16* __restrict__ aux, const float* __restrict__ pos){
    const int row = blockIdx.x * 4 + (threadIdx.x >> 6);
    const int l   = threadIdx.x & 63;
    const float* pa = a + (size_t)row * 128;
    const float* pb = b + (size_t)row * 128;
    float2 va = *(const float2*)&pa[l * 2];
    float2 vb = *(const float2*)&pb[l * 2];
    float x0 = va.x + vb.x, x1 = va.y + vb.y;
    float s = x0 + x1;
#pragma unroll
    for (int m = 32; m >= 1; m >>= 1) s += __shfl_xor(s, m, 64);
    float mean = s * 0.0078125f;
    float e0 = x0 - mean, e1 = x1 - mean;
    float v = e0 * e0 + e1 * e1;
#pragma unroll
    for (int m = 32; m >= 1; m >>= 1) v += __shfl_xor(v, m, 64);
    float rs = rsqrtf(v * 0.0078125f + 1e-5f);
    float2 vg = *(const float2*)&gam[l * 2];
    float2 vt = *(const float2*)&bet[l * 2];
    float2 o;
    o.x = e0 * rs * vg.x + vt.x;
    o.y = e1 * rs * vg.y + vt.y;
    *(float2*)&out[(size_t)row * 128 + l * 2] = o;
    if (MODE == 1){
        ushort2 h; h.x = f2b(o.x); h.y = f2b(o.y);
        *(ushort2*)&aux[(size_t)row * 128 + l * 2] = h;
    } else if (MODE == 2){
        float2 pp = *(const float2*)&pos[(size_t)row * 128 + l * 2];
        ushort2 h; h.x = f2b(o.x + pp.x); h.y = f2b(o.y + pp.y);
        *(ushort2*)&aux[(size_t)row * 128 + l * 2] = h;
    }
}

// =======================================================================
extern "C" void kernel_launch(void* const* d_in, const int* in_sizes, int n_in,
                              void* d_out, int out_size, void* d_ws, size_t ws_size,
                              hipStream_t stream){
    const float* feat0   = (const float*)d_in[0];
    const float* feat1   = (const float*)d_in[1];
    const float* feat2   = (const float*)d_in[2];
    const float* feat3   = (const float*)d_in[3];
    const float* l2i     = (const float*)d_in[4];
    const float* bev_q   = (const float*)d_in[5];
    const float* bev_pos = (const float*)d_in[6];
    const float* pe_w1   = (const float*)d_in[7];
    const float* pe_b1   = (const float*)d_in[8];
    const float* pe_w2   = (const float*)d_in[9];
    const float* pe_b2   = (const float*)d_in[10];
    const float* conv1_w = (const float*)d_in[11];
    const float* conv1_b = (const float*)d_in[12];
    const float* conv2_w = (const float*)d_in[13];
    const float* conv2_b = (const float*)d_in[14];
    const float* off_w   = (const float*)d_in[15];
    const float* off_b   = (const float*)d_in[16];
    const float* sw_w    = (const float*)d_in[17];
    const float* sw_b    = (const float*)d_in[18];
    const float* cp_w1   = (const float*)d_in[19];
    const float* cp_b1   = (const float*)d_in[20];
    const float* cp_w2   = (const float*)d_in[21];
    const float* cp_b2   = (const float*)d_in[22];
    const float* cp_w3   = (const float*)d_in[23];
    const float* cp_b3   = (const float*)d_in[24];
    const float* ffn_w1  = (const float*)d_in[25];
    const float* ffn_b1  = (const float*)d_in[26];
    const float* ffn_w2  = (const float*)d_in[27];
    const float* ffn_b2  = (const float*)d_in[28];
    const float* n1g = (const float*)d_in[29];
    const float* n1b = (const float*)d_in[30];
    const float* n2g = (const float*)d_in[31];
    const float* n2b = (const float*)d_in[32];
    const float* n3g = (const float*)d_in[33];
    const float* n3b = (const float*)d_in[34];

    // ---- workspace layout (float units) ----
    float* base   = (float*)d_ws;
    float* pos    = base;                                  //  5,128,192
    float* qb     = base + 5128192;                        //  5,128,192
    float* hbuf   = base + 10256384;                       // 10,256,384 (h1 full; bufB = first half)
    float* bufB   = hbuf;
    u16*   h1     = (u16*)hbuf;
    u16*   q16    = (u16*)(base + 20512768);               //  2,564,096
    u16*   qpos16 = (u16*)(base + 23076864);               //  2,564,096 (aliased: swuv)
    float* swuv   = (float*)qpos16;
    u16*   bufA16 = (u16*)(base + 25640960);               //  2,564,096 (aliased: osw)
    float* osw    = (float*)bufA16;
    u16*   flat   = (u16*)(base + 28205056);               // 10,256,384
    u16*   ft0    = (u16*)(base + 38461440);
    u16*   ft1    = ft0 + 6 * 32 * 88 * 128;
    u16*   ft2    = ft1 + 6 * 16 * 44 * 128;
    u16*   ft3    = ft2 + 6 * 8 * 22 * 128;
    u16*   w1t    = (u16*)(base + 39897600);               // [512][512]
    u16*   w2t    = (u16*)(base + 40028672);
    u16*   w3t    = (u16*)(base + 40159744);               // [128][512]
    u16*   wc1t   = (u16*)(base + 40192512);               // [128][128]
    u16*   wf1t   = (u16*)(base + 40200704);
    u16*   wf2t   = (u16*)(base + 40208896);
    u16*   owsT   = (u16*)(base + 40217088);               // [32][128]
    float* obias  = (float*)(base + 40219136);             // 32
    u16*   wcs    = (u16*)(base + 40219168);               // 25 x 32KB swizzled
    float* outp   = (float*)d_out;

    // one-time prep
    transpose_feat<<<(6 * 32 * 88 * 32 + 255) / 256, 256, 0, stream>>>(feat0, ft0, 32, 88);
    transpose_feat<<<(6 * 16 * 44 * 32 + 255) / 256, 256, 0, stream>>>(feat1, ft1, 16, 44);
    transpose_feat<<<(6 * 8 * 22 * 32 + 255) / 256, 256, 0, stream>>>(feat2, ft2, 8, 22);
    transpose_feat<<<(6 * 4 * 11 * 32 + 255) / 256, 256, 0, stream>>>(feat3, ft3, 4, 11);
    pos_embed_kernel<<<5000, 256, 0, stream>>>(bev_pos, pe_w1, pe_b1, pe_w2, pe_b2, pos);
    prep_wt<<<(512 * 512 + 255) / 256, 256, 0, stream>>>(cp_w1, w1t, 512, 512);
    prep_wt<<<(512 * 512 + 255) / 256, 256, 0, stream>>>(cp_w2, w2t, 512, 512);
    prep_wt<<<(512 * 128 + 255) / 256, 256, 0, stream>>>(cp_w3, w3t, 512, 128);
    prep_wt<<<(128 * 128 + 255) / 256, 256, 0, stream>>>(conv1_w, wc1t, 128, 128);
    prep_wt<<<(128 * 128 + 255) / 256, 256, 0, stream>>>(ffn_w1, wf1t, 128, 128);
    prep_wt<<<(128 * 128 + 255) / 256, 256, 0, stream>>>(ffn_w2, wf2t, 128, 128);
    prep_osw_w<<<16, 256, 0, stream>>>(off_w, off_b, sw_w, sw_b, owsT, obias);
    prep_conv_w<<<(51200 + 255) / 256, 256, 0, stream>>>(conv2_w, wcs);
    prep_qpos<<<5000, 256, 0, stream>>>(bev_q, pos, qpos16);

    for (int layer = 0; layer < 2; layer++){
        const float* qin = layer ? qb : bev_q;
        // in_conv: 1x1 MFMA GEMM + GELU -> bf16, then 5x5 MFMA conv, then add+LN(n1)+aux bf16
        mfma_gemm<128, 2, u16><<<dim3(313, 1), 256, 0, stream>>>(qpos16, wc1t, conv1_b, bufA16, 128);
        conv5_mfma<<<260, 512, 0, stream>>>(bufA16, wcs, conv2_b, bufB);
        add_ln_kernel<1><<<10000, 256, 0, stream>>>(qin, bufB, n1g, n1b, qb, q16, nullptr);
        // off/sw GEMM -> proj -> sampling
        mfma_osw<<<313, 256, 0, stream>>>(q16, owsT, obias, osw);
        proj_kernel<<<625, 256, 0, stream>>>(osw, bev_pos, l2i, swuv);
        sample_kernel<<<10000, 256, 0, stream>>>(swuv, ft0, ft1, ft2, ft3, flat);
        // compressor MLP (MFMA): 512->512 relu, 512->512 relu, 512->128
        mfma_gemm<512, 1, u16><<<dim3(313, 4), 256, 0, stream>>>(flat, w1t, cp_b1, h1, 512);
        mfma_gemm<512, 1, u16><<<dim3(313, 4), 256, 0, stream>>>(h1, w2t, cp_b2, flat, 512);
        mfma_gemm<512, 0, float><<<dim3(313, 1), 256, 0, stream>>>(flat, w3t, cp_b3, bufB, 128);
        add_ln_kernel<1><<<10000, 256, 0, stream>>>(qb, bufB, n2g, n2b, qb, q16, nullptr);
        // FFN (MFMA)
        mfma_gemm<128, 1, u16><<<dim3(313, 1), 256, 0, stream>>>(q16, wf1t, ffn_b1, bufA16, 128);
        mfma_gemm<128, 0, float><<<dim3(313, 1), 256, 0, stream>>>(bufA16, wf2t, ffn_b2, bufB, 128);
        if (layer == 0)
            add_ln_kernel<2><<<10000, 256, 0, stream>>>(qb, bufB, n3g, n3b, qb, qpos16, pos);
        else
            add_ln_kernel<0><<<10000, 256, 0, stream>>>(qb, bufB, n3g, n3b, outp, nullptr, nullptr);
    }
}

// Round 5
// 618.598 us; speedup vs baseline: 5.4981x; 1.1818x over previous
//
#include <hip/hip_runtime.h>
#include <hip/hip_bf16.h>

typedef unsigned short u16;
typedef __attribute__((ext_vector_type(8))) short bf16x8;
typedef __attribute__((ext_vector_type(4))) float f32x4;

#define DEV __device__ __forceinline__

// ---------- bf16 helpers (storage only; math in f32) ----------
DEV float b2f(u16 s){ return __uint_as_float(((unsigned)s) << 16); }
DEV u16 f2b(float f){
    unsigned u = __float_as_uint(f);
    u = u + 0x7fffu + ((u >> 16) & 1u);   // round-to-nearest-even
    return (u16)(u >> 16);
}
DEV void storeElem(float* p, float v){ *p = v; }
DEV void storeElem(u16* p, float v){ *p = f2b(v); }

template<int ACT> DEV float actf(float x){
    if (ACT == 1) return fmaxf(x, 0.f);
    if (ACT == 2) return 0.5f * x * (1.f + erff(x * 0.70710678118654752f)); // exact GELU
    return x;
}

// async global(16B/lane) -> LDS (wave-uniform base + lane*16)
DEV void gload16(const void* g, void* l){
    __builtin_amdgcn_global_load_lds(
        (const __attribute__((address_space(1))) void*)g,
        (__attribute__((address_space(3))) void*)l, 16, 0, 0);
}

// ---------- feature transpose: (n,C,H,W) f32 -> (n,H,W,C) bf16 ----------
__global__ void transpose_feat(const float* __restrict__ in, u16* __restrict__ out,
                               int H, int W){
    int total = 6 * H * W * 32;                // float4 units
    int lin = blockIdx.x * 256 + threadIdx.x;
    if (lin >= total) return;
    int c4   = (lin & 31) * 4;
    int pix  = lin >> 5;
    int x    = pix % W;
    int rest = pix / W;
    int y    = rest % H;
    int n    = rest / H;
    int HW   = H * W;
    size_t ib = ((size_t)(n * 128 + c4) * H + y) * W + x;
    ushort4 v;
    v.x = f2b(in[ib]);
    v.y = f2b(in[ib + (size_t)HW]);
    v.z = f2b(in[ib + (size_t)2 * HW]);
    v.w = f2b(in[ib + (size_t)3 * HW]);
    *(ushort4*)&out[(size_t)pix * 128 + c4] = v;
}

// ---------- one-time weight prep ----------
// W[K][N] f32 -> WT[N][K] bf16
__global__ void prep_wt(const float* __restrict__ w, u16* __restrict__ o, int K, int N){
    int id = blockIdx.x * 256 + threadIdx.x;
    if (id >= K * N) return;
    int n = id / K, k = id % K;
    o[id] = f2b(w[(size_t)k * N + n]);
}
// combined off/sw weight: owsT[32][128], obias[32]
__global__ void prep_osw_w(const float* __restrict__ off_w, const float* __restrict__ off_b,
                           const float* __restrict__ sw_w, const float* __restrict__ sw_b,
                           u16* __restrict__ owsT, float* __restrict__ obias){
    int id = blockIdx.x * 256 + threadIdx.x;   // 32*128 = 4096
    if (id >= 4096) return;
    int n = id >> 7, k = id & 127;
    float w = (n < 12) ? off_w[k * 12 + n] : (n < 28) ? sw_w[k * 16 + (n - 12)] : 0.f;
    owsT[n * 128 + k] = f2b(w);
    if (k == 0) obias[n] = (n < 12) ? off_b[n] : (n < 28) ? sw_b[n - 12] : 0.f;
}
// conv2_w (5,5,128,128)=[tap][ic][oc] f32 -> per tap, bf16 [oc][ic] pre-swizzled:
// byte = oc*256 + ((slot ^ (oc&15))<<4), slot = ic0/8
__global__ void prep_conv_w(const float* __restrict__ w, u16* __restrict__ o){
    int id = blockIdx.x * 256 + threadIdx.x;   // 25*128*16 = 51200
    if (id >= 51200) return;
    int slot = id & 15;
    int oc   = (id >> 4) & 127;
    int tap  = id >> 11;
    int ic0  = slot * 8;
    u16 tmp[8];
#pragma unroll
    for (int j = 0; j < 8; j++)
        tmp[j] = f2b(w[((size_t)tap * 128 + ic0 + j) * 128 + oc]);
    int baddr = oc * 256 + ((slot ^ (oc & 15)) << 4);
    *(uint4*)((char*)o + (size_t)tap * 32768 + baddr) = *(uint4*)tmp;
}
// qpos16 = bf16(bev_q + pos), 4 elems/thread
__global__ void prep_qpos(const float* __restrict__ q, const float* __restrict__ pos,
                          u16* __restrict__ o){
    int i4 = blockIdx.x * 256 + threadIdx.x;    // 1,280,000 total
    if (i4 >= 1280000) return;
    const float4 a = *(const float4*)&q[(size_t)i4 * 4];
    const float4 p = *(const float4*)&pos[(size_t)i4 * 4];
    ushort4 v; v.x = f2b(a.x + p.x); v.y = f2b(a.y + p.y);
    v.z = f2b(a.z + p.z); v.w = f2b(a.w + p.w);
    *(ushort4*)&o[(size_t)i4 * 4] = v;
}

// ---------- position embedding ----------
__global__ __launch_bounds__(256) void pos_embed_kernel(
    const float* __restrict__ bev_pos,
    const float* __restrict__ w1, const float* __restrict__ b1,
    const float* __restrict__ w2, const float* __restrict__ b2,
    float* __restrict__ pos){
    __shared__ float hid[8][256];
    const int t = threadIdx.x;
    const int q0 = blockIdx.x * 8;
    float wa = w1[t], wb = w1[256 + t], wc = w1[512 + t], bb = b1[t];
#pragma unroll
    for (int qq = 0; qq < 8; qq++){
        float p0 = bev_pos[(q0 + qq) * 3 + 0];
        float p1 = bev_pos[(q0 + qq) * 3 + 1];
        float p2 = bev_pos[(q0 + qq) * 3 + 2];
        hid[qq][t] = fmaxf(p0 * wa + p1 * wb + p2 * wc + bb, 0.f);
    }
    __syncthreads();
    const int oc = t & 127;
    const int qg = (t >> 7) * 4;
    float a0 = 0, a1 = 0, a2 = 0, a3 = 0;
    for (int k = 0; k < 256; k++){
        float w = w2[k * 128 + oc];
        a0 += hid[qg + 0][k] * w;
        a1 += hid[qg + 1][k] * w;
        a2 += hid[qg + 2][k] * w;
        a3 += hid[qg + 3][k] * w;
    }
    float bo = b2[oc];
    pos[(size_t)(q0 + qg + 0) * 128 + oc] = a0 + bo;
    pos[(size_t)(q0 + qg + 1) * 128 + oc] = a1 + bo;
    pos[(size_t)(q0 + qg + 2) * 128 + oc] = a2 + bo;
    pos[(size_t)(q0 + qg + 3) * 128 + oc] = a3 + bo;
}

// ---------- MFMA GEMM: C[M,Ntot] = act(A[M,K]bf16 @ BT[N,K]^T + bias) ----------
DEV void stage64(const u16* __restrict__ g, int ldk, u16* lds, int wv, int lane){
    const u16* gp = g + (size_t)(lane >> 3) * ldk + (lane & 7) * 8;
#pragma unroll
    for (int j = 0; j < 4; j++){
        int ch = wv + j * 4;                 // 16 chunks of 1KB (8 rows each)
        gload16(gp + (size_t)ch * 8 * ldk, lds + ch * 512);
    }
}

template<int K, int ACT, typename TOUT>
__global__ __launch_bounds__(256) void mfma_gemm(
    const u16* __restrict__ A, const u16* __restrict__ BT,
    const float* __restrict__ bias, TOUT* __restrict__ C, int Ntot){
    __shared__ u16 As[2][128 * 64];
    __shared__ u16 Bs[2][128 * 64];
    const int t = threadIdx.x, wv = t >> 6, lane = t & 63;
    const int r0 = blockIdx.x * 128, n0 = blockIdx.y * 128;
    const int l15 = lane & 15, kg = lane >> 4;
    const int wr = (wv >> 1) * 64, wc = (wv & 1) * 64;
    f32x4 acc[4][4];
#pragma unroll
    for (int r = 0; r < 4; r++)
#pragma unroll
        for (int c = 0; c < 4; c++) acc[r][c] = (f32x4){0.f, 0.f, 0.f, 0.f};

    stage64(A + (size_t)r0 * K, K, As[0], wv, lane);
    stage64(BT + (size_t)n0 * K, K, Bs[0], wv, lane);
    __syncthreads();
    int buf = 0;
    for (int kc = 0; kc < K / 64; kc++){
        if (kc + 1 < K / 64){
            stage64(A + (size_t)r0 * K + (kc + 1) * 64, K, As[buf ^ 1], wv, lane);
            stage64(BT + (size_t)n0 * K + (kc + 1) * 64, K, Bs[buf ^ 1], wv, lane);
        }
#pragma unroll
        for (int ks = 0; ks < 2; ks++){
            bf16x8 af[4], bfr[4];
#pragma unroll
            for (int r = 0; r < 4; r++)
                af[r] = *(const bf16x8*)&As[buf][(wr + r * 16 + l15) * 64 + ks * 32 + kg * 8];
#pragma unroll
            for (int c = 0; c < 4; c++)
                bfr[c] = *(const bf16x8*)&Bs[buf][(wc + c * 16 + l15) * 64 + ks * 32 + kg * 8];
#pragma unroll
            for (int r = 0; r < 4; r++)
#pragma unroll
                for (int c = 0; c < 4; c++)
                    acc[r][c] = __builtin_amdgcn_mfma_f32_16x16x32_bf16(af[r], bfr[c], acc[r][c], 0, 0, 0);
        }
        __syncthreads();
        buf ^= 1;
    }
#pragma unroll
    for (int c = 0; c < 4; c++){
        int gcol = n0 + wc + c * 16 + l15;
        float bb = bias[gcol];
#pragma unroll
        for (int r = 0; r < 4; r++){
#pragma unroll
            for (int reg = 0; reg < 4; reg++){
                int grow = r0 + wr + r * 16 + kg * 4 + reg;
                storeElem(C + (size_t)grow * Ntot + gcol, actf<ACT>(acc[r][c][reg] + bb));
            }
        }
    }
}

// ---------- MFMA GEMM fused with residual-add + LayerNorm (Ntot == 128) ----------
// 4 waves; wave tile 32 rows x 128 cols -> each row fully in one wave (LN without LDS).
// AUXM: 0 none, 1 aux=bf16(o), 2 aux=bf16(o+pos)
template<int K, int AUXM>
__global__ __launch_bounds__(256) void mfma_gemm_ln(
    const u16* __restrict__ A, const u16* __restrict__ BT,
    const float* __restrict__ bias, const float* __restrict__ qin,
    const float* __restrict__ gam, const float* __restrict__ bet,
    float* __restrict__ outf, u16* __restrict__ aux,
    const float* __restrict__ pos, int Mlim){
    __shared__ u16 As[2][128 * 64];
    __shared__ u16 Bs[2][128 * 64];
    const int t = threadIdx.x, wv = t >> 6, lane = t & 63;
    const int r0 = blockIdx.x * 128;
    const int l15 = lane & 15, kg = lane >> 4;
    const int wr = wv * 32;
    f32x4 acc[2][8];
#pragma unroll
    for (int r = 0; r < 2; r++)
#pragma unroll
        for (int c = 0; c < 8; c++) acc[r][c] = (f32x4){0.f, 0.f, 0.f, 0.f};

    stage64(A + (size_t)r0 * K, K, As[0], wv, lane);
    stage64(BT, K, Bs[0], wv, lane);
    __syncthreads();
    int buf = 0;
    for (int kc = 0; kc < K / 64; kc++){
        if (kc + 1 < K / 64){
            stage64(A + (size_t)r0 * K + (kc + 1) * 64, K, As[buf ^ 1], wv, lane);
            stage64(BT + (kc + 1) * 64, K, Bs[buf ^ 1], wv, lane);
        }
#pragma unroll
        for (int ks = 0; ks < 2; ks++){
            bf16x8 af[2], bfr[8];
#pragma unroll
            for (int r = 0; r < 2; r++)
                af[r] = *(const bf16x8*)&As[buf][(wr + r * 16 + l15) * 64 + ks * 32 + kg * 8];
#pragma unroll
            for (int c = 0; c < 8; c++)
                bfr[c] = *(const bf16x8*)&Bs[buf][(c * 16 + l15) * 64 + ks * 32 + kg * 8];
#pragma unroll
            for (int r = 0; r < 2; r++)
#pragma unroll
                for (int c = 0; c < 8; c++)
                    acc[r][c] = __builtin_amdgcn_mfma_f32_16x16x32_bf16(af[r], bfr[c], acc[r][c], 0, 0, 0);
        }
        __syncthreads();
        buf ^= 1;
    }
    // epilogue: x = acc + bias + qin; LN over 128 cols (within wave)
    float bb[8], gg[8], be[8];
#pragma unroll
    for (int c = 0; c < 8; c++){
        int col = c * 16 + l15;
        bb[c] = bias[col]; gg[c] = gam[col]; be[c] = bet[col];
    }
#pragma unroll
    for (int r = 0; r < 2; r++){
#pragma unroll
        for (int reg = 0; reg < 4; reg++){
            int grow = r0 + wr + r * 16 + kg * 4 + reg;
            const float* qrow = qin + (size_t)grow * 128;
            float s = 0.f, q2 = 0.f;
#pragma unroll
            for (int c = 0; c < 8; c++){
                float x = acc[r][c][reg] + bb[c] + qrow[c * 16 + l15];
                acc[r][c][reg] = x;
                s += x; q2 += x * x;
            }
#pragma unroll
            for (int m = 8; m >= 1; m >>= 1){
                s  += __shfl_xor(s, m, 64);
                q2 += __shfl_xor(q2, m, 64);
            }
            float mean = s * 0.0078125f;
            float var  = q2 * 0.0078125f - mean * mean;
            float rs   = rsqrtf(var + 1e-5f);
            bool wr_ok = grow < Mlim;
#pragma unroll
            for (int c = 0; c < 8; c++){
                float o = (acc[r][c][reg] - mean) * rs * gg[c] + be[c];
                int col = c * 16 + l15;
                if (wr_ok){
                    outf[(size_t)grow * 128 + col] = o;
                    if (AUXM == 1) aux[(size_t)grow * 128 + col] = f2b(o);
                    else if (AUXM == 2)
                        aux[(size_t)grow * 128 + col] = f2b(o + pos[(size_t)grow * 128 + col]);
                }
            }
        }
    }
}

// ---------- small MFMA GEMM: osw[M][32] = q16[M][128] @ owsT[32][128]^T + obias ----------
__global__ __launch_bounds__(256) void mfma_osw(
    const u16* __restrict__ A, const u16* __restrict__ BT,
    const float* __restrict__ bias, float* __restrict__ osw){
    __shared__ u16 As[2][128 * 64];   // [k-half][row*64 + k']
    __shared__ u16 Bs[2][32 * 64];
    const int t = threadIdx.x, wv = t >> 6, lane = t & 63;
    const int r0 = blockIdx.x * 128;
    const int l15 = lane & 15, kg = lane >> 4;
#pragma unroll
    for (int it = 0; it < 8; it++){
        int id = it * 256 + t;
        int row = id >> 4, slot = id & 15;
        uint4 v = *(const uint4*)&A[(size_t)(r0 + row) * 128 + slot * 8];
        *(uint4*)&As[slot >> 3][row * 64 + (slot & 7) * 8] = v;
    }
#pragma unroll
    for (int it = 0; it < 2; it++){
        int id = it * 256 + t;
        if (id < 512){
            int row = id >> 4, slot = id & 15;
            uint4 v = *(const uint4*)&BT[(size_t)row * 128 + slot * 8];
            *(uint4*)&Bs[slot >> 3][row * 64 + (slot & 7) * 8] = v;
        }
    }
    __syncthreads();
    f32x4 acc[2][2];
#pragma unroll
    for (int r = 0; r < 2; r++)
#pragma unroll
        for (int c = 0; c < 2; c++) acc[r][c] = (f32x4){0.f, 0.f, 0.f, 0.f};
#pragma unroll
    for (int ks = 0; ks < 4; ks++){
        int h = ks >> 1, koff = (ks & 1) * 32 + kg * 8;
        bf16x8 af[2], bfr[2];
#pragma unroll
        for (int r = 0; r < 2; r++)
            af[r] = *(const bf16x8*)&As[h][(wv * 32 + r * 16 + l15) * 64 + koff];
#pragma unroll
        for (int c = 0; c < 2; c++)
            bfr[c] = *(const bf16x8*)&Bs[h][(c * 16 + l15) * 64 + koff];
#pragma unroll
        for (int r = 0; r < 2; r++)
#pragma unroll
            for (int c = 0; c < 2; c++)
                acc[r][c] = __builtin_amdgcn_mfma_f32_16x16x32_bf16(af[r], bfr[c], acc[r][c], 0, 0, 0);
    }
#pragma unroll
    for (int c = 0; c < 2; c++){
        int gcol = c * 16 + l15;
        float bb = bias[gcol];
#pragma unroll
        for (int r = 0; r < 2; r++)
#pragma unroll
            for (int reg = 0; reg < 4; reg++){
                int grow = r0 + wv * 32 + r * 16 + kg * 4 + reg;
                osw[(size_t)grow * 32 + gcol] = acc[r][c][reg] + bb;
            }
    }
}

// ---------- projection: per (q,p): softmax(sw) + 6 cam (u,v) w/ -1 sentinel ----------
__global__ __launch_bounds__(256) void proj_kernel(
    const float* __restrict__ osw, const float* __restrict__ bev_pos,
    const float* __restrict__ l2i, float* __restrict__ swuv){
    int id = blockIdx.x * 256 + threadIdx.x;   // 160000 total
    int qi = id >> 2, p = id & 3;
    const float* row = osw + (size_t)qi * 32;
    float px = bev_pos[qi * 3 + 0] * 100.f - 50.f + row[p * 3 + 0];
    float py = bev_pos[qi * 3 + 1] * 100.f - 50.f + row[p * 3 + 1];
    float pz = bev_pos[qi * 3 + 2] * 8.f   - 5.f  + row[p * 3 + 2];
    float lg[4];
#pragma unroll
    for (int l = 0; l < 4; l++) lg[l] = row[12 + p * 4 + l];
    float mx = fmaxf(fmaxf(lg[0], lg[1]), fmaxf(lg[2], lg[3]));
    float den = 0.f, sw[4];
#pragma unroll
    for (int l = 0; l < 4; l++){ sw[l] = expf(lg[l] - mx); den += sw[l]; }
    float inv = 1.f / den;
    float4 o0; o0.x = sw[0] * inv; o0.y = sw[1] * inv; o0.z = sw[2] * inv; o0.w = sw[3] * inv;
    float uv[12];
#pragma unroll
    for (int cam = 0; cam < 6; cam++){
        const float* M = l2i + cam * 16;
        float t0 = M[0] * px + M[1] * py + M[2]  * pz + M[3];
        float t1 = M[4] * px + M[5] * py + M[6]  * pz + M[7];
        float z  = M[8] * px + M[9] * py + M[10] * pz + M[11];
        float zc = fmaxf(z, 1e-5f);
        float u = t0 / (zc * 704.f);
        float v = t1 / (zc * 256.f);
        bool ok = (z > 1e-5f) && u >= 0.f && u <= 1.f && v >= 0.f && v <= 1.f;
        uv[cam * 2 + 0] = ok ? u : -1.f;
        uv[cam * 2 + 1] = ok ? v : 0.f;
    }
    float* out = swuv + (size_t)id * 16;
    *(float4*)&out[0]  = o0;
    *(float4*)&out[4]  = *(float4*)&uv[0];
    *(float4*)&out[8]  = *(float4*)&uv[4];
    *(float4*)&out[12] = *(float4*)&uv[8];
}

// ---------- deformable sampling: branchless taps. 16 lanes/(q,p), 8 ch/lane ----------
DEV void fma8(float* acc, uint4 v, float w){
    acc[0] = fmaf(__uint_as_float(v.x << 16), w, acc[0]);
    acc[1] = fmaf(__uint_as_float(v.x & 0xffff0000u), w, acc[1]);
    acc[2] = fmaf(__uint_as_float(v.y << 16), w, acc[2]);
    acc[3] = fmaf(__uint_as_float(v.y & 0xffff0000u), w, acc[3]);
    acc[4] = fmaf(__uint_as_float(v.z << 16), w, acc[4]);
    acc[5] = fmaf(__uint_as_float(v.z & 0xffff0000u), w, acc[5]);
    acc[6] = fmaf(__uint_as_float(v.w << 16), w, acc[6]);
    acc[7] = fmaf(__uint_as_float(v.w & 0xffff0000u), w, acc[7]);
}

__global__ __launch_bounds__(256) void sample_kernel(
    const float* __restrict__ swuv,
    const u16* __restrict__ f0, const u16* __restrict__ f1,
    const u16* __restrict__ f2, const u16* __restrict__ f3,
    u16* __restrict__ flat){
    const int t = threadIdx.x;
    const int lane = t & 15;
    const int id = blockIdx.x * 16 + (t >> 4);
    const int d0 = lane * 8;
    const float* sp = swuv + (size_t)id * 16;
    float4 sw = *(const float4*)sp;
    float swl[4] = {sw.x, sw.y, sw.z, sw.w};
    float acc[8] = {0, 0, 0, 0, 0, 0, 0, 0};
    const int HS[4] = {32, 16, 8, 4};
    const int WS[4] = {88, 44, 22, 11};
#pragma unroll
    for (int cam = 0; cam < 6; cam++){
        float u = sp[4 + cam * 2], v = sp[5 + cam * 2];
        if (u < 0.f) continue;
#pragma unroll
        for (int l = 0; l < 4; l++){
            const int Hl = HS[l], Wl = WS[l];
            const u16* fb = (l == 0 ? f0 : l == 1 ? f1 : l == 2 ? f2 : f3)
                          + (size_t)cam * (Hl * Wl * 128) + d0;
            float xx = u * (float)Wl - 0.5f;
            float yy = v * (float)Hl - 0.5f;
            float xf = floorf(xx), yf = floorf(yy);
            float wx = xx - xf, wy = yy - yf;
            int ix = (int)xf, iy = (int)yf;
            float sl = swl[l];
            float wx0 = (ix >= 0)      ? 1.f - wx : 0.f;
            float wx1 = (ix < Wl - 1)  ? wx       : 0.f;
            float wy0 = (iy >= 0)      ? 1.f - wy : 0.f;
            float wy1 = (iy < Hl - 1)  ? wy       : 0.f;
            int x0c = max(ix, 0), x1c = min(ix + 1, Wl - 1);
            int y0c = max(iy, 0), y1c = min(iy + 1, Hl - 1);
            const u16* r0p = fb + (size_t)(y0c * Wl) * 128;
            const u16* r1p = fb + (size_t)(y1c * Wl) * 128;
            uint4 v00 = *(const uint4*)(r0p + (size_t)x0c * 128);
            uint4 v10 = *(const uint4*)(r0p + (size_t)x1c * 128);
            uint4 v01 = *(const uint4*)(r1p + (size_t)x0c * 128);
            uint4 v11 = *(const uint4*)(r1p + (size_t)x1c * 128);
            fma8(acc, v00, sl * wx0 * wy0);
            fma8(acc, v10, sl * wx1 * wy0);
            fma8(acc, v01, sl * wx0 * wy1);
            fma8(acc, v11, sl * wx1 * wy1);
        }
    }
    uint4 o;
    o.x = (unsigned)f2b(acc[0]) | ((unsigned)f2b(acc[1]) << 16);
    o.y = (unsigned)f2b(acc[2]) | ((unsigned)f2b(acc[3]) << 16);
    o.z = (unsigned)f2b(acc[4]) | ((unsigned)f2b(acc[5]) << 16);
    o.w = (unsigned)f2b(acc[6]) | ((unsigned)f2b(acc[7]) << 16);
    *(uint4*)&flat[(size_t)id * 128 + d0] = o;
}

// ---------- 5x5 conv via MFMA implicit GEMM ----------
// 256 threads = 4 waves (2M x 2N). Tile: 96 px (8y x 12x) x 128 oc.
// Grid 25y x 17x = 425 blocks; LDS = 48KB patch + 32KB weights = 80KB -> 2 blocks/CU.
// Patch swizzle: byte = pix*256 + ((slot ^ (pix&15) ^ (pix>>4)) << 4)  [pix = pr*16+pc]
__global__ __launch_bounds__(256) void conv5_mfma(
    const u16* __restrict__ in,     // [200][200][128] bf16
    const u16* __restrict__ wswz,   // [25] x 32KB pre-swizzled [oc][ic] bf16
    const float* __restrict__ bias,
    float* __restrict__ out){       // [200][200][128] f32
    __shared__ u16 Ps[192 * 128];       // 49152 B
    __shared__ u16 Bs[128 * 128];       // 32768 B
    const int t = threadIdx.x, wv = t >> 6, lane = t & 63;
    const int bx = blockIdx.x % 17, by = blockIdx.x / 17;
    const int x0 = bx * 12, y0 = by * 8;
    const int l15 = lane & 15, kg = lane >> 4;
    const int wr = (wv >> 1) * 48, wc = (wv & 1) * 64;

    // patch staging: 192 px (12 rows x 16 cols) x 16 slots of 16B, guarded, swizzled
#pragma unroll
    for (int it = 0; it < 12; it++){
        int id = it * 256 + t;
        int pix = id >> 4, slot = id & 15;
        int pr = pix >> 4, pc = pix & 15;
        int gy = y0 + pr - 2, gx = x0 + pc - 2;
        uint4 v = {0u, 0u, 0u, 0u};
        if (gy >= 0 && gy < 200 && gx >= 0 && gx < 200)
            v = *(const uint4*)&in[(size_t)(gy * 200 + gx) * 128 + slot * 8];
        int baddr = pix * 256 + (((slot ^ pc ^ pr) & 15) << 4);
        *(uint4*)((char*)Ps + baddr) = v;
    }
    // stage tap 0 weights (32 chunks of 1KB, 8 per wave)
#pragma unroll
    for (int j = 0; j < 8; j++){
        int ch = wv * 8 + j;
        gload16(wswz + ch * 512 + lane * 8, (u16*)Bs + ch * 512);
    }
    // per-lane A-row geometry (3 M-frags of 16 rows)
    int mbase[3], pxr[3];
#pragma unroll
    for (int r = 0; r < 3; r++){
        int m = wr + r * 16 + l15;
        int py = m / 12, px = m - py * 12;
        mbase[r] = py * 16 + px;
        pxr[r] = px;
    }
    f32x4 acc[3][4];
#pragma unroll
    for (int r = 0; r < 3; r++)
#pragma unroll
        for (int c = 0; c < 4; c++) acc[r][c] = (f32x4){0.f, 0.f, 0.f, 0.f};
    __syncthreads();

    for (int tap = 0; tap < 25; tap++){
        const int ky = tap / 5, kx = tap % 5;
        const int tapoff = ky * 16 + kx;
        int swzA[3];
#pragma unroll
        for (int r = 0; r < 3; r++)
            swzA[r] = ((pxr[r] + kx) ^ ((mbase[r] >> 4) + ky)) & 15;
#pragma unroll
        for (int ks = 0; ks < 4; ks++){
            const int slot = ks * 4 + kg;
            bf16x8 af[3], bfr[2];
#pragma unroll
            for (int r = 0; r < 3; r++){
                int baddr = (mbase[r] + tapoff) * 256 + (((slot ^ swzA[r]) & 15) << 4);
                af[r] = *(const bf16x8*)((const char*)Ps + baddr);
            }
#pragma unroll
            for (int c = 0; c < 2; c++){
                int oc = wc + c * 16 + l15;
                int baddr = oc * 256 + (((slot ^ l15) & 15) << 4);
                bfr[c] = *(const bf16x8*)((const char*)Bs + baddr);
            }
#pragma unroll
            for (int r = 0; r < 3; r++){
                acc[r][0] = __builtin_amdgcn_mfma_f32_16x16x32_bf16(af[r], bfr[0], acc[r][0], 0, 0, 0);
                acc[r][1] = __builtin_amdgcn_mfma_f32_16x16x32_bf16(af[r], bfr[1], acc[r][1], 0, 0, 0);
            }
            bf16x8 bfr2[2];
#pragma unroll
            for (int c = 0; c < 2; c++){
                int oc = wc + (c + 2) * 16 + l15;
                int baddr = oc * 256 + (((slot ^ l15) & 15) << 4);
                bfr2[c] = *(const bf16x8*)((const char*)Bs + baddr);
            }
#pragma unroll
            for (int r = 0; r < 3; r++){
                acc[r][2] = __builtin_amdgcn_mfma_f32_16x16x32_bf16(af[r], bfr2[0], acc[r][2], 0, 0, 0);
                acc[r][3] = __builtin_amdgcn_mfma_f32_16x16x32_bf16(af[r], bfr2[1], acc[r][3], 0, 0, 0);
            }
        }
        __syncthreads();
        if (tap < 24){
            const u16* wt = wswz + (size_t)(tap + 1) * 16384;
#pragma unroll
            for (int j = 0; j < 8; j++){
                int ch = wv * 8 + j;
                gload16(wt + ch * 512 + lane * 8, (u16*)Bs + ch * 512);
            }
            __syncthreads();
        }
    }
#pragma unroll
    for (int c = 0; c < 4; c++){
        int oc = wc + c * 16 + l15;
        float bb = bias[oc];
#pragma unroll
        for (int r = 0; r < 3; r++){
#pragma unroll
            for (int reg = 0; reg < 4; reg++){
                int m = wr + r * 16 + kg * 4 + reg;
                int py = m / 12, px = m - py * 12;
                int gx = x0 + px;
                if (gx < 200)
                    out[(size_t)((y0 + py) * 200 + gx) * 128 + oc] = acc[r][c][reg] + bb;
            }
        }
    }
}

// ---------- residual add + LayerNorm (MODE: 0 none, 1 aux=bf16(out), 2 aux=bf16(out+pos)) ----------
template<int MODE>
__global__ __launch_bounds__(256) void add_ln_kernel(
    const float* __restrict__ a, const float* __restrict__ b,
    const float* __restrict__ gam, const float* __restrict__ bet,
    float* __restrict__ out, u16* __restrict__ aux, const float* __restrict__ pos){
    const int row = blockIdx.x * 4 + (threadIdx.x >> 6);
    const int l   = threadIdx.x & 63;
    const float* pa = a + (size_t)row * 128;
    const float* pb = b + (size_t)row * 128;
    float2 va = *(const float2*)&pa[l * 2];
    float2 vb = *(const float2*)&pb[l * 2];
    float x0 = va.x + vb.x, x1 = va.y + vb.y;
    float s = x0 + x1;
#pragma unroll
    for (int m = 32; m >= 1; m >>= 1) s += __shfl_xor(s, m, 64);
    float mean = s * 0.0078125f;
    float e0 = x0 - mean, e1 = x1 - mean;
    float v = e0 * e0 + e1 * e1;
#pragma unroll
    for (int m = 32; m >= 1; m >>= 1) v += __shfl_xor(v, m, 64);
    float rs = rsqrtf(v * 0.0078125f + 1e-5f);
    float2 vg = *(const float2*)&gam[l * 2];
    float2 vt = *(const float2*)&bet[l * 2];
    float2 o;
    o.x = e0 * rs * vg.x + vt.x;
    o.y = e1 * rs * vg.y + vt.y;
    *(float2*)&out[(size_t)row * 128 + l * 2] = o;
    if (MODE == 1){
        ushort2 h; h.x = f2b(o.x); h.y = f2b(o.y);
        *(ushort2*)&aux[(size_t)row * 128 + l * 2] = h;
    } else if (MODE == 2){
        float2 pp = *(const float2*)&pos[(size_t)row * 128 + l * 2];
        ushort2 h; h.x = f2b(o.x + pp.x); h.y = f2b(o.y + pp.y);
        *(ushort2*)&aux[(size_t)row * 128 + l * 2] = h;
    }
}

// =======================================================================
extern "C" void kernel_launch(void* const* d_in, const int* in_sizes, int n_in,
                              void* d_out, int out_size, void* d_ws, size_t ws_size,
                              hipStream_t stream){
    const float* feat0   = (const float*)d_in[0];
    const float* feat1   = (const float*)d_in[1];
    const float* feat2   = (const float*)d_in[2];
    const float* feat3   = (const float*)d_in[3];
    const float* l2i     = (const float*)d_in[4];
    const float* bev_q   = (const float*)d_in[5];
    const float* bev_pos = (const float*)d_in[6];
    const float* pe_w1   = (const float*)d_in[7];
    const float* pe_b1   = (const float*)d_in[8];
    const float* pe_w2   = (const float*)d_in[9];
    const float* pe_b2   = (const float*)d_in[10];
    const float* conv1_w = (const float*)d_in[11];
    const float* conv1_b = (const float*)d_in[12];
    const float* conv2_w = (const float*)d_in[13];
    const float* conv2_b = (const float*)d_in[14];
    const float* off_w   = (const float*)d_in[15];
    const float* off_b   = (const float*)d_in[16];
    const float* sw_w    = (const float*)d_in[17];
    const float* sw_b    = (const float*)d_in[18];
    const float* cp_w1   = (const float*)d_in[19];
    const float* cp_b1   = (const float*)d_in[20];
    const float* cp_w2   = (const float*)d_in[21];
    const float* cp_b2   = (const float*)d_in[22];
    const float* cp_w3   = (const float*)d_in[23];
    const float* cp_b3   = (const float*)d_in[24];
    const float* ffn_w1  = (const float*)d_in[25];
    const float* ffn_b1  = (const float*)d_in[26];
    const float* ffn_w2  = (const float*)d_in[27];
    const float* ffn_b2  = (const float*)d_in[28];
    const float* n1g = (const float*)d_in[29];
    const float* n1b = (const float*)d_in[30];
    const float* n2g = (const float*)d_in[31];
    const float* n2b = (const float*)d_in[32];
    const float* n3g = (const float*)d_in[33];
    const float* n3b = (const float*)d_in[34];

    // ---- workspace layout (float units) ----
    float* base   = (float*)d_ws;
    float* pos    = base;                                  //  5,128,192
    float* qb     = base + 5128192;                        //  5,128,192
    float* hbuf   = base + 10256384;                       // 10,256,384 (h1 full; bufB = first half)
    float* bufB   = hbuf;
    u16*   h1     = (u16*)hbuf;
    u16*   q16    = (u16*)(base + 20512768);               //  2,564,096
    u16*   qpos16 = (u16*)(base + 23076864);               //  2,564,096 (aliased: swuv)
    float* swuv   = (float*)qpos16;
    u16*   bufA16 = (u16*)(base + 25640960);               //  2,564,096 (aliased: osw)
    float* osw    = (float*)bufA16;
    u16*   flat   = (u16*)(base + 28205056);               // 10,256,384
    u16*   ft0    = (u16*)(base + 38461440);
    u16*   ft1    = ft0 + 6 * 32 * 88 * 128;
    u16*   ft2    = ft1 + 6 * 16 * 44 * 128;
    u16*   ft3    = ft2 + 6 * 8 * 22 * 128;
    u16*   w1t    = (u16*)(base + 39897600);               // [512][512]
    u16*   w2t    = (u16*)(base + 40028672);
    u16*   w3t    = (u16*)(base + 40159744);               // [128][512]
    u16*   wc1t   = (u16*)(base + 40192512);               // [128][128]
    u16*   wf1t   = (u16*)(base + 40200704);
    u16*   wf2t   = (u16*)(base + 40208896);
    u16*   owsT   = (u16*)(base + 40217088);               // [32][128]
    float* obias  = (float*)(base + 40219136);             // 32
    u16*   wcs    = (u16*)(base + 40219168);               // 25 x 32KB swizzled
    float* outp   = (float*)d_out;

    // one-time prep
    transpose_feat<<<(6 * 32 * 88 * 32 + 255) / 256, 256, 0, stream>>>(feat0, ft0, 32, 88);
    transpose_feat<<<(6 * 16 * 44 * 32 + 255) / 256, 256, 0, stream>>>(feat1, ft1, 16, 44);
    transpose_feat<<<(6 * 8 * 22 * 32 + 255) / 256, 256, 0, stream>>>(feat2, ft2, 8, 22);
    transpose_feat<<<(6 * 4 * 11 * 32 + 255) / 256, 256, 0, stream>>>(feat3, ft3, 4, 11);
    pos_embed_kernel<<<5000, 256, 0, stream>>>(bev_pos, pe_w1, pe_b1, pe_w2, pe_b2, pos);
    prep_wt<<<(512 * 512 + 255) / 256, 256, 0, stream>>>(cp_w1, w1t, 512, 512);
    prep_wt<<<(512 * 512 + 255) / 256, 256, 0, stream>>>(cp_w2, w2t, 512, 512);
    prep_wt<<<(512 * 128 + 255) / 256, 256, 0, stream>>>(cp_w3, w3t, 512, 128);
    prep_wt<<<(128 * 128 + 255) / 256, 256, 0, stream>>>(conv1_w, wc1t, 128, 128);
    prep_wt<<<(128 * 128 + 255) / 256, 256, 0, stream>>>(ffn_w1, wf1t, 128, 128);
    prep_wt<<<(128 * 128 + 255) / 256, 256, 0, stream>>>(ffn_w2, wf2t, 128, 128);
    prep_osw_w<<<16, 256, 0, stream>>>(off_w, off_b, sw_w, sw_b, owsT, obias);
    prep_conv_w<<<(51200 + 255) / 256, 256, 0, stream>>>(conv2_w, wcs);
    prep_qpos<<<5000, 256, 0, stream>>>(bev_q, pos, qpos16);

    for (int layer = 0; layer < 2; layer++){
        const float* qin = layer ? qb : bev_q;
        // in_conv: 1x1 MFMA GEMM + GELU -> bf16, then 5x5 MFMA conv, then add+LN(n1)+aux bf16
        mfma_gemm<128, 2, u16><<<dim3(313, 1), 256, 0, stream>>>(qpos16, wc1t, conv1_b, bufA16, 128);
        conv5_mfma<<<425, 256, 0, stream>>>(bufA16, wcs, conv2_b, bufB);
        add_ln_kernel<1><<<10000, 256, 0, stream>>>(qin, bufB, n1g, n1b, qb, q16, nullptr);
        // off/sw GEMM -> proj -> sampling
        mfma_osw<<<313, 256, 0, stream>>>(q16, owsT, obias, osw);
        proj_kernel<<<625, 256, 0, stream>>>(osw, bev_pos, l2i, swuv);
        sample_kernel<<<10000, 256, 0, stream>>>(swuv, ft0, ft1, ft2, ft3, flat);
        // compressor MLP (MFMA): 512->512 relu, 512->512 relu, then fused 512->128 + add + LN(n2)
        mfma_gemm<512, 1, u16><<<dim3(313, 4), 256, 0, stream>>>(flat, w1t, cp_b1, h1, 512);
        mfma_gemm<512, 1, u16><<<dim3(313, 4), 256, 0, stream>>>(h1, w2t, cp_b2, flat, 512);
        mfma_gemm_ln<512, 1><<<313, 256, 0, stream>>>(flat, w3t, cp_b3, qb, n2g, n2b,
                                                      qb, q16, nullptr, 40064);
        // FFN: relu GEMM, then fused GEMM + add + LN(n3)
        mfma_gemm<128, 1, u16><<<dim3(313, 1), 256, 0, stream>>>(q16, wf1t, ffn_b1, bufA16, 128);
        if (layer == 0)
            mfma_gemm_ln<128, 2><<<313, 256, 0, stream>>>(bufA16, wf2t, ffn_b2, qb, n3g, n3b,
                                                          qb, qpos16, pos, 40064);
        else
            mfma_gemm_ln<128, 0><<<313, 256, 0, stream>>>(bufA16, wf2t, ffn_b2, qb, n3g, n3b,
                                                          outp, nullptr, nullptr, 40000);
    }
}

// Round 6
// 567.780 us; speedup vs baseline: 5.9901x; 1.0895x over previous
//
#include <hip/hip_runtime.h>
#include <hip/hip_bf16.h>

typedef unsigned short u16;
typedef __attribute__((ext_vector_type(8))) short bf16x8;
typedef __attribute__((ext_vector_type(4))) float f32x4;

#define DEV __device__ __forceinline__

// ---------- bf16 helpers (storage only; math in f32) ----------
DEV float b2f(u16 s){ return __uint_as_float(((unsigned)s) << 16); }
DEV u16 f2b(float f){
    unsigned u = __float_as_uint(f);
    u = u + 0x7fffu + ((u >> 16) & 1u);   // round-to-nearest-even
    return (u16)(u >> 16);
}
DEV void storeElem(float* p, float v){ *p = v; }
DEV void storeElem(u16* p, float v){ *p = f2b(v); }

template<int ACT> DEV float actf(float x){
    if (ACT == 1) return fmaxf(x, 0.f);
    if (ACT == 2) return 0.5f * x * (1.f + erff(x * 0.70710678118654752f)); // exact GELU
    return x;
}

// async global(16B/lane) -> LDS (wave-uniform base + lane*16)
DEV void gload16(const void* g, void* l){
    __builtin_amdgcn_global_load_lds(
        (const __attribute__((address_space(1))) void*)g,
        (__attribute__((address_space(3))) void*)l, 16, 0, 0);
}

// ---------- feature transpose: (n,C,H,W) f32 -> (n,H,W,C) bf16 ----------
__global__ void transpose_feat(const float* __restrict__ in, u16* __restrict__ out,
                               int H, int W){
    int total = 6 * H * W * 32;                // float4 units
    int lin = blockIdx.x * 256 + threadIdx.x;
    if (lin >= total) return;
    int c4   = (lin & 31) * 4;
    int pix  = lin >> 5;
    int x    = pix % W;
    int rest = pix / W;
    int y    = rest % H;
    int n    = rest / H;
    int HW   = H * W;
    size_t ib = ((size_t)(n * 128 + c4) * H + y) * W + x;
    ushort4 v;
    v.x = f2b(in[ib]);
    v.y = f2b(in[ib + (size_t)HW]);
    v.z = f2b(in[ib + (size_t)2 * HW]);
    v.w = f2b(in[ib + (size_t)3 * HW]);
    *(ushort4*)&out[(size_t)pix * 128 + c4] = v;
}

// ---------- one-time weight prep ----------
// W[K][N] f32 -> WT[N][K] bf16
__global__ void prep_wt(const float* __restrict__ w, u16* __restrict__ o, int K, int N){
    int id = blockIdx.x * 256 + threadIdx.x;
    if (id >= K * N) return;
    int n = id / K, k = id % K;
    o[id] = f2b(w[(size_t)k * N + n]);
}
// combined off/sw weight: owsT[32][128], obias[32]
__global__ void prep_osw_w(const float* __restrict__ off_w, const float* __restrict__ off_b,
                           const float* __restrict__ sw_w, const float* __restrict__ sw_b,
                           u16* __restrict__ owsT, float* __restrict__ obias){
    int id = blockIdx.x * 256 + threadIdx.x;   // 32*128 = 4096
    if (id >= 4096) return;
    int n = id >> 7, k = id & 127;
    float w = (n < 12) ? off_w[k * 12 + n] : (n < 28) ? sw_w[k * 16 + (n - 12)] : 0.f;
    owsT[n * 128 + k] = f2b(w);
    if (k == 0) obias[n] = (n < 12) ? off_b[n] : (n < 28) ? sw_b[n - 12] : 0.f;
}
// conv2_w (5,5,128,128)=[tap][ic][oc] f32 -> per tap, bf16 [oc][ic] pre-swizzled:
// byte = oc*256 + ((slot ^ (oc&15))<<4), slot = ic0/8
__global__ void prep_conv_w(const float* __restrict__ w, u16* __restrict__ o){
    int id = blockIdx.x * 256 + threadIdx.x;   // 25*128*16 = 51200
    if (id >= 51200) return;
    int slot = id & 15;
    int oc   = (id >> 4) & 127;
    int tap  = id >> 11;
    int ic0  = slot * 8;
    u16 tmp[8];
#pragma unroll
    for (int j = 0; j < 8; j++)
        tmp[j] = f2b(w[((size_t)tap * 128 + ic0 + j) * 128 + oc]);
    int baddr = oc * 256 + ((slot ^ (oc & 15)) << 4);
    *(uint4*)((char*)o + (size_t)tap * 32768 + baddr) = *(uint4*)tmp;
}
// qpos16 = bf16(bev_q + pos), 4 elems/thread
__global__ void prep_qpos(const float* __restrict__ q, const float* __restrict__ pos,
                          u16* __restrict__ o){
    int i4 = blockIdx.x * 256 + threadIdx.x;    // 1,280,000 total
    if (i4 >= 1280000) return;
    const float4 a = *(const float4*)&q[(size_t)i4 * 4];
    const float4 p = *(const float4*)&pos[(size_t)i4 * 4];
    ushort4 v; v.x = f2b(a.x + p.x); v.y = f2b(a.y + p.y);
    v.z = f2b(a.z + p.z); v.w = f2b(a.w + p.w);
    *(ushort4*)&o[(size_t)i4 * 4] = v;
}
// hid = bf16(relu(bev_pos @ pe_w1 + pe_b1)) : [40000][256]
__global__ void prep_hid(const float* __restrict__ bev_pos,
                         const float* __restrict__ w1, const float* __restrict__ b1,
                         u16* __restrict__ hid){
    int id = blockIdx.x * 256 + threadIdx.x;   // 40000*64
    if (id >= 2560000) return;
    int qi = id >> 6, c4 = (id & 63) * 4;
    float p0 = bev_pos[qi * 3 + 0];
    float p1 = bev_pos[qi * 3 + 1];
    float p2 = bev_pos[qi * 3 + 2];
    ushort4 v;
    u16* vp = (u16*)&v;
#pragma unroll
    for (int j = 0; j < 4; j++){
        int ch = c4 + j;
        float h = p0 * w1[ch] + p1 * w1[256 + ch] + p2 * w1[512 + ch] + b1[ch];
        vp[j] = f2b(fmaxf(h, 0.f));
    }
    *(ushort4*)&hid[(size_t)qi * 256 + c4] = v;
}

// ---------- MFMA GEMM: C[M,Ntot] = act(A[M,K]bf16 @ BT[N,K]^T + bias) ----------
DEV void stage64(const u16* __restrict__ g, int ldk, u16* lds, int wv, int lane){
    const u16* gp = g + (size_t)(lane >> 3) * ldk + (lane & 7) * 8;
#pragma unroll
    for (int j = 0; j < 4; j++){
        int ch = wv + j * 4;                 // 16 chunks of 1KB (8 rows each)
        gload16(gp + (size_t)ch * 8 * ldk, lds + ch * 512);
    }
}

template<int K, int ACT, typename TOUT>
__global__ __launch_bounds__(256) void mfma_gemm(
    const u16* __restrict__ A, const u16* __restrict__ BT,
    const float* __restrict__ bias, TOUT* __restrict__ C, int Ntot){
    __shared__ u16 As[2][128 * 64];
    __shared__ u16 Bs[2][128 * 64];
    const int t = threadIdx.x, wv = t >> 6, lane = t & 63;
    const int r0 = blockIdx.x * 128, n0 = blockIdx.y * 128;
    const int l15 = lane & 15, kg = lane >> 4;
    const int wr = (wv >> 1) * 64, wc = (wv & 1) * 64;
    f32x4 acc[4][4];
#pragma unroll
    for (int r = 0; r < 4; r++)
#pragma unroll
        for (int c = 0; c < 4; c++) acc[r][c] = (f32x4){0.f, 0.f, 0.f, 0.f};

    stage64(A + (size_t)r0 * K, K, As[0], wv, lane);
    stage64(BT + (size_t)n0 * K, K, Bs[0], wv, lane);
    __syncthreads();
    int buf = 0;
    for (int kc = 0; kc < K / 64; kc++){
        if (kc + 1 < K / 64){
            stage64(A + (size_t)r0 * K + (kc + 1) * 64, K, As[buf ^ 1], wv, lane);
            stage64(BT + (size_t)n0 * K + (kc + 1) * 64, K, Bs[buf ^ 1], wv, lane);
        }
#pragma unroll
        for (int ks = 0; ks < 2; ks++){
            bf16x8 af[4], bfr[4];
#pragma unroll
            for (int r = 0; r < 4; r++)
                af[r] = *(const bf16x8*)&As[buf][(wr + r * 16 + l15) * 64 + ks * 32 + kg * 8];
#pragma unroll
            for (int c = 0; c < 4; c++)
                bfr[c] = *(const bf16x8*)&Bs[buf][(wc + c * 16 + l15) * 64 + ks * 32 + kg * 8];
#pragma unroll
            for (int r = 0; r < 4; r++)
#pragma unroll
                for (int c = 0; c < 4; c++)
                    acc[r][c] = __builtin_amdgcn_mfma_f32_16x16x32_bf16(af[r], bfr[c], acc[r][c], 0, 0, 0);
        }
        __syncthreads();
        buf ^= 1;
    }
#pragma unroll
    for (int c = 0; c < 4; c++){
        int gcol = n0 + wc + c * 16 + l15;
        float bb = bias[gcol];
#pragma unroll
        for (int r = 0; r < 4; r++){
#pragma unroll
            for (int reg = 0; reg < 4; reg++){
                int grow = r0 + wr + r * 16 + kg * 4 + reg;
                storeElem(C + (size_t)grow * Ntot + gcol, actf<ACT>(acc[r][c][reg] + bb));
            }
        }
    }
}

// ---------- MFMA GEMM fused with residual-add + LayerNorm (Ntot == 128) ----------
// 4 waves; wave tile 32 rows x 128 cols -> each row fully in one wave (LN without LDS).
// AUXM: 0 none, 1 aux=bf16(o), 2 aux=bf16(o+pos)
template<int K, int AUXM>
__global__ __launch_bounds__(256) void mfma_gemm_ln(
    const u16* __restrict__ A, const u16* __restrict__ BT,
    const float* __restrict__ bias, const float* __restrict__ qin,
    const float* __restrict__ gam, const float* __restrict__ bet,
    float* __restrict__ outf, u16* __restrict__ aux,
    const float* __restrict__ pos, int Mlim){
    __shared__ u16 As[2][128 * 64];
    __shared__ u16 Bs[2][128 * 64];
    const int t = threadIdx.x, wv = t >> 6, lane = t & 63;
    const int r0 = blockIdx.x * 128;
    const int l15 = lane & 15, kg = lane >> 4;
    const int wr = wv * 32;
    f32x4 acc[2][8];
#pragma unroll
    for (int r = 0; r < 2; r++)
#pragma unroll
        for (int c = 0; c < 8; c++) acc[r][c] = (f32x4){0.f, 0.f, 0.f, 0.f};

    stage64(A + (size_t)r0 * K, K, As[0], wv, lane);
    stage64(BT, K, Bs[0], wv, lane);
    __syncthreads();
    int buf = 0;
    for (int kc = 0; kc < K / 64; kc++){
        if (kc + 1 < K / 64){
            stage64(A + (size_t)r0 * K + (kc + 1) * 64, K, As[buf ^ 1], wv, lane);
            stage64(BT + (kc + 1) * 64, K, Bs[buf ^ 1], wv, lane);
        }
#pragma unroll
        for (int ks = 0; ks < 2; ks++){
            bf16x8 af[2], bfr[8];
#pragma unroll
            for (int r = 0; r < 2; r++)
                af[r] = *(const bf16x8*)&As[buf][(wr + r * 16 + l15) * 64 + ks * 32 + kg * 8];
#pragma unroll
            for (int c = 0; c < 8; c++)
                bfr[c] = *(const bf16x8*)&Bs[buf][(c * 16 + l15) * 64 + ks * 32 + kg * 8];
#pragma unroll
            for (int r = 0; r < 2; r++)
#pragma unroll
                for (int c = 0; c < 8; c++)
                    acc[r][c] = __builtin_amdgcn_mfma_f32_16x16x32_bf16(af[r], bfr[c], acc[r][c], 0, 0, 0);
        }
        __syncthreads();
        buf ^= 1;
    }
    // epilogue: x = acc + bias + qin; LN over 128 cols (within wave)
    float bb[8], gg[8], be[8];
#pragma unroll
    for (int c = 0; c < 8; c++){
        int col = c * 16 + l15;
        bb[c] = bias[col]; gg[c] = gam[col]; be[c] = bet[col];
    }
#pragma unroll
    for (int r = 0; r < 2; r++){
#pragma unroll
        for (int reg = 0; reg < 4; reg++){
            int grow = r0 + wr + r * 16 + kg * 4 + reg;
            const float* qrow = qin + (size_t)grow * 128;
            float s = 0.f, q2 = 0.f;
#pragma unroll
            for (int c = 0; c < 8; c++){
                float x = acc[r][c][reg] + bb[c] + qrow[c * 16 + l15];
                acc[r][c][reg] = x;
                s += x; q2 += x * x;
            }
#pragma unroll
            for (int m = 8; m >= 1; m >>= 1){
                s  += __shfl_xor(s, m, 64);
                q2 += __shfl_xor(q2, m, 64);
            }
            float mean = s * 0.0078125f;
            float var  = q2 * 0.0078125f - mean * mean;
            float rs   = rsqrtf(var + 1e-5f);
            bool wr_ok = grow < Mlim;
#pragma unroll
            for (int c = 0; c < 8; c++){
                float o = (acc[r][c][reg] - mean) * rs * gg[c] + be[c];
                int col = c * 16 + l15;
                if (wr_ok){
                    outf[(size_t)grow * 128 + col] = o;
                    if (AUXM == 1) aux[(size_t)grow * 128 + col] = f2b(o);
                    else if (AUXM == 2)
                        aux[(size_t)grow * 128 + col] = f2b(o + pos[(size_t)grow * 128 + col]);
                }
            }
        }
    }
}

// ---------- small MFMA GEMM: osw[M][32] = q16[M][128] @ owsT[32][128]^T + obias ----------
__global__ __launch_bounds__(256) void mfma_osw(
    const u16* __restrict__ A, const u16* __restrict__ BT,
    const float* __restrict__ bias, float* __restrict__ osw){
    __shared__ u16 As[2][128 * 64];   // [k-half][row*64 + k']
    __shared__ u16 Bs[2][32 * 64];
    const int t = threadIdx.x, wv = t >> 6, lane = t & 63;
    const int r0 = blockIdx.x * 128;
    const int l15 = lane & 15, kg = lane >> 4;
#pragma unroll
    for (int it = 0; it < 8; it++){
        int id = it * 256 + t;
        int row = id >> 4, slot = id & 15;
        uint4 v = *(const uint4*)&A[(size_t)(r0 + row) * 128 + slot * 8];
        *(uint4*)&As[slot >> 3][row * 64 + (slot & 7) * 8] = v;
    }
#pragma unroll
    for (int it = 0; it < 2; it++){
        int id = it * 256 + t;
        if (id < 512){
            int row = id >> 4, slot = id & 15;
            uint4 v = *(const uint4*)&BT[(size_t)row * 128 + slot * 8];
            *(uint4*)&Bs[slot >> 3][row * 64 + (slot & 7) * 8] = v;
        }
    }
    __syncthreads();
    f32x4 acc[2][2];
#pragma unroll
    for (int r = 0; r < 2; r++)
#pragma unroll
        for (int c = 0; c < 2; c++) acc[r][c] = (f32x4){0.f, 0.f, 0.f, 0.f};
#pragma unroll
    for (int ks = 0; ks < 4; ks++){
        int h = ks >> 1, koff = (ks & 1) * 32 + kg * 8;
        bf16x8 af[2], bfr[2];
#pragma unroll
        for (int r = 0; r < 2; r++)
            af[r] = *(const bf16x8*)&As[h][(wv * 32 + r * 16 + l15) * 64 + koff];
#pragma unroll
        for (int c = 0; c < 2; c++)
            bfr[c] = *(const bf16x8*)&Bs[h][(c * 16 + l15) * 64 + koff];
#pragma unroll
        for (int r = 0; r < 2; r++)
#pragma unroll
            for (int c = 0; c < 2; c++)
                acc[r][c] = __builtin_amdgcn_mfma_f32_16x16x32_bf16(af[r], bfr[c], acc[r][c], 0, 0, 0);
    }
#pragma unroll
    for (int c = 0; c < 2; c++){
        int gcol = c * 16 + l15;
        float bb = bias[gcol];
#pragma unroll
        for (int r = 0; r < 2; r++)
#pragma unroll
            for (int reg = 0; reg < 4; reg++){
                int grow = r0 + wv * 32 + r * 16 + kg * 4 + reg;
                osw[(size_t)grow * 32 + gcol] = acc[r][c][reg] + bb;
            }
    }
}

// ---------- projection: per (q,p): softmax(sw) + 6 cam (u,v) w/ -1 sentinel ----------
__global__ __launch_bounds__(256) void proj_kernel(
    const float* __restrict__ osw, const float* __restrict__ bev_pos,
    const float* __restrict__ l2i, float* __restrict__ swuv){
    int id = blockIdx.x * 256 + threadIdx.x;   // 160000 total
    int qi = id >> 2, p = id & 3;
    const float* row = osw + (size_t)qi * 32;
    float px = bev_pos[qi * 3 + 0] * 100.f - 50.f + row[p * 3 + 0];
    float py = bev_pos[qi * 3 + 1] * 100.f - 50.f + row[p * 3 + 1];
    float pz = bev_pos[qi * 3 + 2] * 8.f   - 5.f  + row[p * 3 + 2];
    float lg[4];
#pragma unroll
    for (int l = 0; l < 4; l++) lg[l] = row[12 + p * 4 + l];
    float mx = fmaxf(fmaxf(lg[0], lg[1]), fmaxf(lg[2], lg[3]));
    float den = 0.f, sw[4];
#pragma unroll
    for (int l = 0; l < 4; l++){ sw[l] = expf(lg[l] - mx); den += sw[l]; }
    float inv = 1.f / den;
    float4 o0; o0.x = sw[0] * inv; o0.y = sw[1] * inv; o0.z = sw[2] * inv; o0.w = sw[3] * inv;
    float uv[12];
#pragma unroll
    for (int cam = 0; cam < 6; cam++){
        const float* M = l2i + cam * 16;
        float t0 = M[0] * px + M[1] * py + M[2]  * pz + M[3];
        float t1 = M[4] * px + M[5] * py + M[6]  * pz + M[7];
        float z  = M[8] * px + M[9] * py + M[10] * pz + M[11];
        float zc = fmaxf(z, 1e-5f);
        float u = t0 / (zc * 704.f);
        float v = t1 / (zc * 256.f);
        bool ok = (z > 1e-5f) && u >= 0.f && u <= 1.f && v >= 0.f && v <= 1.f;
        uv[cam * 2 + 0] = ok ? u : -1.f;
        uv[cam * 2 + 1] = ok ? v : 0.f;
    }
    float* out = swuv + (size_t)id * 16;
    *(float4*)&out[0]  = o0;
    *(float4*)&out[4]  = *(float4*)&uv[0];
    *(float4*)&out[8]  = *(float4*)&uv[4];
    *(float4*)&out[12] = *(float4*)&uv[8];
}

// ---------- deformable sampling: branchless taps. 16 lanes/(q,p), 8 ch/lane ----------
DEV void fma8(float* acc, uint4 v, float w){
    acc[0] = fmaf(__uint_as_float(v.x << 16), w, acc[0]);
    acc[1] = fmaf(__uint_as_float(v.x & 0xffff0000u), w, acc[1]);
    acc[2] = fmaf(__uint_as_float(v.y << 16), w, acc[2]);
    acc[3] = fmaf(__uint_as_float(v.y & 0xffff0000u), w, acc[3]);
    acc[4] = fmaf(__uint_as_float(v.z << 16), w, acc[4]);
    acc[5] = fmaf(__uint_as_float(v.z & 0xffff0000u), w, acc[5]);
    acc[6] = fmaf(__uint_as_float(v.w << 16), w, acc[6]);
    acc[7] = fmaf(__uint_as_float(v.w & 0xffff0000u), w, acc[7]);
}

__global__ __launch_bounds__(256) void sample_kernel(
    const float* __restrict__ swuv,
    const u16* __restrict__ f0, const u16* __restrict__ f1,
    const u16* __restrict__ f2, const u16* __restrict__ f3,
    u16* __restrict__ flat){
    const int t = threadIdx.x;
    const int lane = t & 15;
    const int id = blockIdx.x * 16 + (t >> 4);
    const int d0 = lane * 8;
    const float* sp = swuv + (size_t)id * 16;
    float4 sw = *(const float4*)sp;
    float swl[4] = {sw.x, sw.y, sw.z, sw.w};
    float acc[8] = {0, 0, 0, 0, 0, 0, 0, 0};
    const int HS[4] = {32, 16, 8, 4};
    const int WS[4] = {88, 44, 22, 11};
#pragma unroll
    for (int cam = 0; cam < 6; cam++){
        float u = sp[4 + cam * 2], v = sp[5 + cam * 2];
        if (u < 0.f) continue;
#pragma unroll
        for (int l = 0; l < 4; l++){
            const int Hl = HS[l], Wl = WS[l];
            const u16* fb = (l == 0 ? f0 : l == 1 ? f1 : l == 2 ? f2 : f3)
                          + (size_t)cam * (Hl * Wl * 128) + d0;
            float xx = u * (float)Wl - 0.5f;
            float yy = v * (float)Hl - 0.5f;
            float xf = floorf(xx), yf = floorf(yy);
            float wx = xx - xf, wy = yy - yf;
            int ix = (int)xf, iy = (int)yf;
            float sl = swl[l];
            float wx0 = (ix >= 0)      ? 1.f - wx : 0.f;
            float wx1 = (ix < Wl - 1)  ? wx       : 0.f;
            float wy0 = (iy >= 0)      ? 1.f - wy : 0.f;
            float wy1 = (iy < Hl - 1)  ? wy       : 0.f;
            int x0c = max(ix, 0), x1c = min(ix + 1, Wl - 1);
            int y0c = max(iy, 0), y1c = min(iy + 1, Hl - 1);
            const u16* r0p = fb + (size_t)(y0c * Wl) * 128;
            const u16* r1p = fb + (size_t)(y1c * Wl) * 128;
            uint4 v00 = *(const uint4*)(r0p + (size_t)x0c * 128);
            uint4 v10 = *(const uint4*)(r0p + (size_t)x1c * 128);
            uint4 v01 = *(const uint4*)(r1p + (size_t)x0c * 128);
            uint4 v11 = *(const uint4*)(r1p + (size_t)x1c * 128);
            fma8(acc, v00, sl * wx0 * wy0);
            fma8(acc, v10, sl * wx1 * wy0);
            fma8(acc, v01, sl * wx0 * wy1);
            fma8(acc, v11, sl * wx1 * wy1);
        }
    }
    uint4 o;
    o.x = (unsigned)f2b(acc[0]) | ((unsigned)f2b(acc[1]) << 16);
    o.y = (unsigned)f2b(acc[2]) | ((unsigned)f2b(acc[3]) << 16);
    o.z = (unsigned)f2b(acc[4]) | ((unsigned)f2b(acc[5]) << 16);
    o.w = (unsigned)f2b(acc[6]) | ((unsigned)f2b(acc[7]) << 16);
    *(uint4*)&flat[(size_t)id * 128 + d0] = o;
}

// ---------- 5x5 conv via MFMA implicit GEMM, fused residual + LN(n1) ----------
// 256 threads = 4 waves (2M x 2N). Tile: 96 px (8y x 12x) x 128 oc.
// Grid 25y x 17x = 425 blocks; LDS = 48KB patch + 32KB weights = 80KB -> 2 blocks/CU.
__global__ __launch_bounds__(256) void conv5_ln(
    const u16* __restrict__ in,     // [200][200][128] bf16
    const u16* __restrict__ wswz,   // [25] x 32KB pre-swizzled [oc][ic] bf16
    const float* __restrict__ bias,
    const float* __restrict__ qin,  // residual input (f32, 40000x128)
    const float* __restrict__ gam, const float* __restrict__ bet,
    float* __restrict__ qb, u16* __restrict__ q16){
    __shared__ u16 Ps[192 * 128];       // 49152 B
    __shared__ u16 Bs[128 * 128];       // 32768 B
    const int t = threadIdx.x, wv = t >> 6, lane = t & 63;
    const int bx = blockIdx.x % 17, by = blockIdx.x / 17;
    const int x0 = bx * 12, y0 = by * 8;
    const int l15 = lane & 15, kg = lane >> 4;
    const int wr = (wv >> 1) * 48, wc = (wv & 1) * 64;

    // patch staging: 192 px (12 rows x 16 cols) x 16 slots of 16B, guarded, swizzled
#pragma unroll
    for (int it = 0; it < 12; it++){
        int id = it * 256 + t;
        int pix = id >> 4, slot = id & 15;
        int pr = pix >> 4, pc = pix & 15;
        int gy = y0 + pr - 2, gx = x0 + pc - 2;
        uint4 v = {0u, 0u, 0u, 0u};
        if (gy >= 0 && gy < 200 && gx >= 0 && gx < 200)
            v = *(const uint4*)&in[(size_t)(gy * 200 + gx) * 128 + slot * 8];
        int baddr = pix * 256 + (((slot ^ pc ^ pr) & 15) << 4);
        *(uint4*)((char*)Ps + baddr) = v;
    }
    // stage tap 0 weights (32 chunks of 1KB, 8 per wave)
#pragma unroll
    for (int j = 0; j < 8; j++){
        int ch = wv * 8 + j;
        gload16(wswz + ch * 512 + lane * 8, (u16*)Bs + ch * 512);
    }
    // per-lane A-row geometry (3 M-frags of 16 rows)
    int mbase[3], pxr[3];
#pragma unroll
    for (int r = 0; r < 3; r++){
        int m = wr + r * 16 + l15;
        int py = m / 12, px = m - py * 12;
        mbase[r] = py * 16 + px;
        pxr[r] = px;
    }
    f32x4 acc[3][4];
#pragma unroll
    for (int r = 0; r < 3; r++)
#pragma unroll
        for (int c = 0; c < 4; c++) acc[r][c] = (f32x4){0.f, 0.f, 0.f, 0.f};
    __syncthreads();

    for (int tap = 0; tap < 25; tap++){
        const int ky = tap / 5, kx = tap % 5;
        const int tapoff = ky * 16 + kx;
        int swzA[3];
#pragma unroll
        for (int r = 0; r < 3; r++)
            swzA[r] = ((pxr[r] + kx) ^ ((mbase[r] >> 4) + ky)) & 15;
#pragma unroll
        for (int ks = 0; ks < 4; ks++){
            const int slot = ks * 4 + kg;
            bf16x8 af[3], bfr[2];
#pragma unroll
            for (int r = 0; r < 3; r++){
                int baddr = (mbase[r] + tapoff) * 256 + (((slot ^ swzA[r]) & 15) << 4);
                af[r] = *(const bf16x8*)((const char*)Ps + baddr);
            }
#pragma unroll
            for (int c = 0; c < 2; c++){
                int oc = wc + c * 16 + l15;
                int baddr = oc * 256 + (((slot ^ l15) & 15) << 4);
                bfr[c] = *(const bf16x8*)((const char*)Bs + baddr);
            }
#pragma unroll
            for (int r = 0; r < 3; r++){
                acc[r][0] = __builtin_amdgcn_mfma_f32_16x16x32_bf16(af[r], bfr[0], acc[r][0], 0, 0, 0);
                acc[r][1] = __builtin_amdgcn_mfma_f32_16x16x32_bf16(af[r], bfr[1], acc[r][1], 0, 0, 0);
            }
            bf16x8 bfr2[2];
#pragma unroll
            for (int c = 0; c < 2; c++){
                int oc = wc + (c + 2) * 16 + l15;
                int baddr = oc * 256 + (((slot ^ l15) & 15) << 4);
                bfr2[c] = *(const bf16x8*)((const char*)Bs + baddr);
            }
#pragma unroll
            for (int r = 0; r < 3; r++){
                acc[r][2] = __builtin_amdgcn_mfma_f32_16x16x32_bf16(af[r], bfr2[0], acc[r][2], 0, 0, 0);
                acc[r][3] = __builtin_amdgcn_mfma_f32_16x16x32_bf16(af[r], bfr2[1], acc[r][3], 0, 0, 0);
            }
        }
        __syncthreads();
        if (tap < 24){
            const u16* wt = wswz + (size_t)(tap + 1) * 16384;
#pragma unroll
            for (int j = 0; j < 8; j++){
                int ch = wv * 8 + j;
                gload16(wt + ch * 512 + lane * 8, (u16*)Bs + ch * 512);
            }
            __syncthreads();
        }
    }
    // ---- fused residual + LayerNorm epilogue (Ps is dead; overlay partials) ----
    float* part = (float*)Ps;   // [96][2 sides][2] f32
    float bb[4], gg[4], be[4];
#pragma unroll
    for (int c = 0; c < 4; c++){
        int oc = wc + c * 16 + l15;
        bb[c] = bias[oc]; gg[c] = gam[oc]; be[c] = bet[oc];
    }
#pragma unroll
    for (int r = 0; r < 3; r++){
#pragma unroll
        for (int reg = 0; reg < 4; reg++){
            int m = wr + r * 16 + kg * 4 + reg;
            int py = m / 12, px = m - py * 12;
            int grow = (y0 + py) * 200 + x0 + px;
            int growc = min(grow, 39999);
            const float* qrow = qin + (size_t)growc * 128;
            float s = 0.f, q2 = 0.f;
#pragma unroll
            for (int c = 0; c < 4; c++){
                float x = acc[r][c][reg] + bb[c] + qrow[wc + c * 16 + l15];
                acc[r][c][reg] = x;
                s += x; q2 += x * x;
            }
#pragma unroll
            for (int msk = 8; msk >= 1; msk >>= 1){
                s  += __shfl_xor(s, msk, 64);
                q2 += __shfl_xor(q2, msk, 64);
            }
            if (l15 == 0){
                part[m * 4 + (wv & 1) * 2 + 0] = s;
                part[m * 4 + (wv & 1) * 2 + 1] = q2;
            }
        }
    }
    __syncthreads();
#pragma unroll
    for (int r = 0; r < 3; r++){
#pragma unroll
        for (int reg = 0; reg < 4; reg++){
            int m = wr + r * 16 + kg * 4 + reg;
            int py = m / 12, px = m - py * 12;
            int gx = x0 + px;
            if (gx >= 200) continue;
            int grow = (y0 + py) * 200 + gx;
            float s  = part[m * 4 + 0] + part[m * 4 + 2];
            float q2 = part[m * 4 + 1] + part[m * 4 + 3];
            float mean = s * 0.0078125f;
            float var  = q2 * 0.0078125f - mean * mean;
            float rs   = rsqrtf(var + 1e-5f);
#pragma unroll
            for (int c = 0; c < 4; c++){
                int oc = wc + c * 16 + l15;
                float o = (acc[r][c][reg] - mean) * rs * gg[c] + be[c];
                qb[(size_t)grow * 128 + oc]  = o;
                q16[(size_t)grow * 128 + oc] = f2b(o);
            }
        }
    }
}

// =======================================================================
extern "C" void kernel_launch(void* const* d_in, const int* in_sizes, int n_in,
                              void* d_out, int out_size, void* d_ws, size_t ws_size,
                              hipStream_t stream){
    const float* feat0   = (const float*)d_in[0];
    const float* feat1   = (const float*)d_in[1];
    const float* feat2   = (const float*)d_in[2];
    const float* feat3   = (const float*)d_in[3];
    const float* l2i     = (const float*)d_in[4];
    const float* bev_q   = (const float*)d_in[5];
    const float* bev_pos = (const float*)d_in[6];
    const float* pe_w1   = (const float*)d_in[7];
    const float* pe_b1   = (const float*)d_in[8];
    const float* pe_w2   = (const float*)d_in[9];
    const float* pe_b2   = (const float*)d_in[10];
    const float* conv1_w = (const float*)d_in[11];
    const float* conv1_b = (const float*)d_in[12];
    const float* conv2_w = (const float*)d_in[13];
    const float* conv2_b = (const float*)d_in[14];
    const float* off_w   = (const float*)d_in[15];
    const float* off_b   = (const float*)d_in[16];
    const float* sw_w    = (const float*)d_in[17];
    const float* sw_b    = (const float*)d_in[18];
    const float* cp_w1   = (const float*)d_in[19];
    const float* cp_b1   = (const float*)d_in[20];
    const float* cp_w2   = (const float*)d_in[21];
    const float* cp_b2   = (const float*)d_in[22];
    const float* cp_w3   = (const float*)d_in[23];
    const float* cp_b3   = (const float*)d_in[24];
    const float* ffn_w1  = (const float*)d_in[25];
    const float* ffn_b1  = (const float*)d_in[26];
    const float* ffn_w2  = (const float*)d_in[27];
    const float* ffn_b2  = (const float*)d_in[28];
    const float* n1g = (const float*)d_in[29];
    const float* n1b = (const float*)d_in[30];
    const float* n2g = (const float*)d_in[31];
    const float* n2b = (const float*)d_in[32];
    const float* n3g = (const float*)d_in[33];
    const float* n3b = (const float*)d_in[34];

    // ---- workspace layout (float units) ----
    float* base   = (float*)d_ws;
    float* pos    = base;                                  //  5,128,192
    float* qb     = base + 5128192;                        //  5,128,192
    float* hbuf   = base + 10256384;                       // 10,256,384 (h1)
    u16*   h1     = (u16*)hbuf;
    u16*   q16    = (u16*)(base + 20512768);               //  2,564,096
    u16*   qpos16 = (u16*)(base + 23076864);               //  2,564,096 (aliased: swuv)
    float* swuv   = (float*)qpos16;
    u16*   bufA16 = (u16*)(base + 25640960);               //  2,564,096 (aliased: osw)
    float* osw    = (float*)bufA16;
    u16*   flat   = (u16*)(base + 28205056);               // 10,256,384 (prep alias: hid16)
    u16*   hid16  = flat;                                  // [40064][256] bf16 (prep only)
    u16*   ft0    = (u16*)(base + 38461440);
    u16*   ft1    = ft0 + 6 * 32 * 88 * 128;
    u16*   ft2    = ft1 + 6 * 16 * 44 * 128;
    u16*   ft3    = ft2 + 6 * 8 * 22 * 128;
    u16*   w1t    = (u16*)(base + 39897600);               // [512][512]
    u16*   w2t    = (u16*)(base + 40028672);
    u16*   w3t    = (u16*)(base + 40159744);               // [128][512]
    u16*   wc1t   = (u16*)(base + 40192512);               // [128][128]
    u16*   wf1t   = (u16*)(base + 40200704);
    u16*   wf2t   = (u16*)(base + 40208896);
    u16*   owsT   = (u16*)(base + 40217088);               // [32][128]
    float* obias  = (float*)(base + 40219136);             // 32
    u16*   wcs    = (u16*)(base + 40219168);               // 25 x 32KB swizzled
    u16*   pw2t   = (u16*)(base + 40424168);               // [128][256] bf16
    float* outp   = (float*)d_out;

    // one-time prep
    transpose_feat<<<(6 * 32 * 88 * 32 + 255) / 256, 256, 0, stream>>>(feat0, ft0, 32, 88);
    transpose_feat<<<(6 * 16 * 44 * 32 + 255) / 256, 256, 0, stream>>>(feat1, ft1, 16, 44);
    transpose_feat<<<(6 * 8 * 22 * 32 + 255) / 256, 256, 0, stream>>>(feat2, ft2, 8, 22);
    transpose_feat<<<(6 * 4 * 11 * 32 + 255) / 256, 256, 0, stream>>>(feat3, ft3, 4, 11);
    prep_wt<<<(512 * 512 + 255) / 256, 256, 0, stream>>>(cp_w1, w1t, 512, 512);
    prep_wt<<<(512 * 512 + 255) / 256, 256, 0, stream>>>(cp_w2, w2t, 512, 512);
    prep_wt<<<(512 * 128 + 255) / 256, 256, 0, stream>>>(cp_w3, w3t, 512, 128);
    prep_wt<<<(128 * 128 + 255) / 256, 256, 0, stream>>>(conv1_w, wc1t, 128, 128);
    prep_wt<<<(128 * 128 + 255) / 256, 256, 0, stream>>>(ffn_w1, wf1t, 128, 128);
    prep_wt<<<(128 * 128 + 255) / 256, 256, 0, stream>>>(ffn_w2, wf2t, 128, 128);
    prep_wt<<<(256 * 128 + 255) / 256, 256, 0, stream>>>(pe_w2, pw2t, 256, 128);
    prep_osw_w<<<16, 256, 0, stream>>>(off_w, off_b, sw_w, sw_b, owsT, obias);
    prep_conv_w<<<(51200 + 255) / 256, 256, 0, stream>>>(conv2_w, wcs);
    // position embedding via MFMA: hid = bf16(relu(pos@W1+b1)); pos = hid @ W2^T + b2
    prep_hid<<<10000, 256, 0, stream>>>(bev_pos, pe_w1, pe_b1, hid16);
    mfma_gemm<256, 0, float><<<dim3(313, 1), 256, 0, stream>>>(hid16, pw2t, pe_b2, pos, 128);
    prep_qpos<<<5000, 256, 0, stream>>>(bev_q, pos, qpos16);

    for (int layer = 0; layer < 2; layer++){
        const float* qin = layer ? qb : bev_q;
        // in_conv: 1x1 MFMA GEMM + GELU -> bf16, then 5x5 MFMA conv + add + LN(n1) fused
        mfma_gemm<128, 2, u16><<<dim3(313, 1), 256, 0, stream>>>(qpos16, wc1t, conv1_b, bufA16, 128);
        conv5_ln<<<425, 256, 0, stream>>>(bufA16, wcs, conv2_b, qin, n1g, n1b, qb, q16);
        // off/sw GEMM -> proj -> sampling
        mfma_osw<<<313, 256, 0, stream>>>(q16, owsT, obias, osw);
        proj_kernel<<<625, 256, 0, stream>>>(osw, bev_pos, l2i, swuv);
        sample_kernel<<<10000, 256, 0, stream>>>(swuv, ft0, ft1, ft2, ft3, flat);
        // compressor MLP (MFMA): 512->512 relu, 512->512 relu, then fused 512->128 + add + LN(n2)
        mfma_gemm<512, 1, u16><<<dim3(313, 4), 256, 0, stream>>>(flat, w1t, cp_b1, h1, 512);
        mfma_gemm<512, 1, u16><<<dim3(313, 4), 256, 0, stream>>>(h1, w2t, cp_b2, flat, 512);
        mfma_gemm_ln<512, 1><<<313, 256, 0, stream>>>(flat, w3t, cp_b3, qb, n2g, n2b,
                                                      qb, q16, nullptr, 40064);
        // FFN: relu GEMM, then fused GEMM + add + LN(n3)
        mfma_gemm<128, 1, u16><<<dim3(313, 1), 256, 0, stream>>>(q16, wf1t, ffn_b1, bufA16, 128);
        if (layer == 0)
            mfma_gemm_ln<128, 2><<<313, 256, 0, stream>>>(bufA16, wf2t, ffn_b2, qb, n3g, n3b,
                                                          qb, qpos16, pos, 40064);
        else
            mfma_gemm_ln<128, 0><<<313, 256, 0, stream>>>(bufA16, wf2t, ffn_b2, qb, n3g, n3b,
                                                          outp, nullptr, nullptr, 40000);
    }
}